// Round 1
// baseline (39746.881 us; speedup 1.0000x reference)
//
#include <hip/hip_runtime.h>
#include <hip/hip_bf16.h>

#define RR 8
#define DD 128
#define HH 4

__device__ __forceinline__ unsigned encf(float f){
  unsigned u = __float_as_uint(f);
  return (u & 0x80000000u) ? ~u : (u | 0x80000000u);
}
__device__ __forceinline__ float decf(unsigned u){
  return (u & 0x80000000u) ? __uint_as_float(u & 0x7FFFFFFFu) : __uint_as_float(~u);
}
__device__ __forceinline__ float leaky(float x, float s){ return x > 0.f ? x : s * x; }

// W[r,i,o] = sum_b comp[r,b] * basis[b,i,o]   (R*D*D = 131072 threads exactly)
__global__ void k_make_W(const float* __restrict__ basis, const float* __restrict__ comp,
                         float* __restrict__ W){
  int idx = blockIdx.x * 256 + threadIdx.x;
  int r = idx >> 14, io = idx & 16383;
  float s = 0.f;
  #pragma unroll
  for (int b = 0; b < 8; b++) s += comp[r * 8 + b] * basis[b * 16384 + io];
  W[idx] = s;
}

__global__ void k_deg(const int* __restrict__ et, const int* __restrict__ dst,
                      float* __restrict__ deg, int E_, int N_){
  int e = blockIdx.x * 256 + threadIdx.x;
  if (e < E_) atomicAdd(&deg[(size_t)et[e] * N_ + dst[e]], 1.0f);
}

__global__ void k_recip(float* __restrict__ deg, int n){
  int i = blockIdx.x * 256 + threadIdx.x;
  if (i < n) deg[i] = 1.0f / fmaxf(deg[i], 1.0f);
}

// C[row, c] (=/+=) scale[row] * sum_k A[row,k]*Wm[k,c]  (+ bias[c] on init)
// A is [nrows,128] row-major. Wm is [128, ld] row-major. C is [nrows, ld].
// Block: 256 thr = 2 row-groups x 128 cols; 8 rows/block; thread does 4 rows x 1 col.
__launch_bounds__(256)
__global__ void k_gemm(const float* __restrict__ A, const float* __restrict__ Wm,
                       const float* __restrict__ bias, const float* __restrict__ scale,
                       float* __restrict__ C, int ld, int accumulate){
  int c    = (threadIdx.x & 127) + (blockIdx.y << 7);
  int rg   = threadIdx.x >> 7;
  int row0 = blockIdx.x * 8 + rg * 4;
  const float4* A4 = (const float4*)(A + (size_t)row0 * DD);
  float acc0 = 0.f, acc1 = 0.f, acc2 = 0.f, acc3 = 0.f;
  #pragma unroll
  for (int k4 = 0; k4 < 32; k4++){
    float4 a0 = A4[k4], a1 = A4[32 + k4], a2 = A4[64 + k4], a3 = A4[96 + k4];
    const float* wpt = Wm + (size_t)(k4 * 4) * ld + c;
    float w0 = wpt[0], w1 = wpt[ld], w2 = wpt[2 * ld], w3 = wpt[3 * ld];
    acc0 += a0.x * w0; acc1 += a1.x * w0; acc2 += a2.x * w0; acc3 += a3.x * w0;
    acc0 += a0.y * w1; acc1 += a1.y * w1; acc2 += a2.y * w1; acc3 += a3.y * w1;
    acc0 += a0.z * w2; acc1 += a1.z * w2; acc2 += a2.z * w2; acc3 += a3.z * w2;
    acc0 += a0.w * w3; acc1 += a1.w * w3; acc2 += a2.w * w3; acc3 += a3.w * w3;
  }
  float s0 = 1.f, s1 = 1.f, s2 = 1.f, s3 = 1.f;
  if (scale){ s0 = scale[row0]; s1 = scale[row0 + 1]; s2 = scale[row0 + 2]; s3 = scale[row0 + 3]; }
  size_t o = (size_t)row0 * ld + c;
  if (accumulate){
    C[o]          += acc0 * s0;
    C[o + ld]     += acc1 * s1;
    C[o + 2 * ld] += acc2 * s2;
    C[o + 3 * ld] += acc3 * s3;
  } else {
    float bb = bias ? bias[c & 127] : 0.f;
    C[o]          = acc0 * s0 + bb;
    C[o + ld]     = acc1 * s1 + bb;
    C[o + 2 * ld] = acc2 * s2 + bb;
    C[o + 3 * ld] = acc3 * s3 + bb;
  }
}

// agg[dst,:] += X[src,:] for edges of relation r. 2 edges per block of 256.
__global__ void k_scatter(const int* __restrict__ src, const int* __restrict__ dst,
                          const int* __restrict__ et, int r, const float* __restrict__ X,
                          float* __restrict__ agg, int E_){
  int e = blockIdx.x * 2 + (threadIdx.x >> 7);
  if (e >= E_ || et[e] != r) return;
  int d = threadIdx.x & 127;
  atomicAdd(&agg[(size_t)dst[e] * DD + d], X[(size_t)src[e] * DD + d]);
}

// In-place LayerNorm over 128 feats + leaky_relu. One wave per row, 4 rows/block.
__global__ void k_ln_leaky(float* __restrict__ X, const float* __restrict__ g,
                           const float* __restrict__ b, float slope){
  int row  = blockIdx.x * 4 + (threadIdx.x >> 6);
  int lane = threadIdx.x & 63;
  float2 v = *(float2*)(X + (size_t)row * DD + lane * 2);
  float s = v.x + v.y;
  for (int o = 1; o < 64; o <<= 1) s += __shfl_xor(s, o);
  float mu = s * (1.f / 128.f);
  float dx = v.x - mu, dy = v.y - mu;
  float q = dx * dx + dy * dy;
  for (int o = 1; o < 64; o <<= 1) q += __shfl_xor(q, o);
  float rstd = rsqrtf(q * (1.f / 128.f) + 1e-5f);
  float2 gg = *(const float2*)(g + lane * 2), bb = *(const float2*)(b + lane * 2);
  float y0 = dx * rstd * gg.x + bb.x;
  float y1 = dy * rstd * gg.y + bb.y;
  y0 = leaky(y0, slope); y1 = leaky(y1, slope);
  *(float2*)(X + (size_t)row * DD + lane * 2) = make_float2(y0, y1);
}

// aS[n,h] = hH[n,h,:]·a_src[h,:], aD likewise. One wave per node (16 lanes/head).
__global__ void k_alpha(const float* __restrict__ hH, const float* __restrict__ a_src,
                        const float* __restrict__ a_dst, float* __restrict__ aS,
                        float* __restrict__ aD){
  int node = blockIdx.x * 4 + (threadIdx.x >> 6);
  int lane = threadIdx.x & 63;
  int h = lane >> 4, dgrp = lane & 15;
  const float4* p  = (const float4*)(hH + (size_t)node * 512 + h * 128 + dgrp * 8);
  const float4* s4 = (const float4*)(a_src + h * 128 + dgrp * 8);
  const float4* d4 = (const float4*)(a_dst + h * 128 + dgrp * 8);
  float4 v0 = p[0], v1 = p[1];
  float4 as0 = s4[0], as1 = s4[1], ad0 = d4[0], ad1 = d4[1];
  float ss = v0.x*as0.x + v0.y*as0.y + v0.z*as0.z + v0.w*as0.w
           + v1.x*as1.x + v1.y*as1.y + v1.z*as1.z + v1.w*as1.w;
  float sd = v0.x*ad0.x + v0.y*ad0.y + v0.z*ad0.z + v0.w*ad0.w
           + v1.x*ad1.x + v1.y*ad1.y + v1.z*ad1.z + v1.w*ad1.w;
  for (int o = 1; o < 16; o <<= 1){ ss += __shfl_xor(ss, o); sd += __shfl_xor(sd, o); }
  if (dgrp == 0){ aS[(size_t)node * 4 + h] = ss; aD[(size_t)node * 4 + h] = sd; }
}

// Items 0..E-1 are edges; E..E+N-1 are self loops.
__global__ void k_edge_max(const int* __restrict__ src, const int* __restrict__ dst,
                           const float* __restrict__ aS, const float* __restrict__ aD,
                           unsigned* __restrict__ mx, int E_, int N_){
  int i = blockIdx.x * 256 + threadIdx.x;
  if (i >= E_ + N_) return;
  int s, t;
  if (i < E_){ s = src[i]; t = dst[i]; } else { s = i - E_; t = s; }
  float4 a = *(const float4*)(aS + (size_t)s * 4);
  float4 b = *(const float4*)(aD + (size_t)t * 4);
  float e0 = leaky(a.x + b.x, 0.2f), e1 = leaky(a.y + b.y, 0.2f);
  float e2 = leaky(a.z + b.z, 0.2f), e3 = leaky(a.w + b.w, 0.2f);
  atomicMax(&mx[(size_t)t * 4 + 0], encf(e0));
  atomicMax(&mx[(size_t)t * 4 + 1], encf(e1));
  atomicMax(&mx[(size_t)t * 4 + 2], encf(e2));
  atomicMax(&mx[(size_t)t * 4 + 3], encf(e3));
}

__global__ void k_edge_exp(const int* __restrict__ src, const int* __restrict__ dst,
                           const float* __restrict__ aS, const float* __restrict__ aD,
                           const unsigned* __restrict__ mx, float* __restrict__ den,
                           float* __restrict__ cf, int E_, int N_){
  int i = blockIdx.x * 256 + threadIdx.x;
  if (i >= E_ + N_) return;
  int s, t;
  if (i < E_){ s = src[i]; t = dst[i]; } else { s = i - E_; t = s; }
  float4 a = *(const float4*)(aS + (size_t)s * 4);
  float4 b = *(const float4*)(aD + (size_t)t * 4);
  float e0 = leaky(a.x + b.x, 0.2f), e1 = leaky(a.y + b.y, 0.2f);
  float e2 = leaky(a.z + b.z, 0.2f), e3 = leaky(a.w + b.w, 0.2f);
  float x0 = expf(e0 - decf(mx[(size_t)t * 4 + 0]));
  float x1 = expf(e1 - decf(mx[(size_t)t * 4 + 1]));
  float x2 = expf(e2 - decf(mx[(size_t)t * 4 + 2]));
  float x3 = expf(e3 - decf(mx[(size_t)t * 4 + 3]));
  *(float4*)(cf + (size_t)i * 4) = make_float4(x0, x1, x2, x3);
  atomicAdd(&den[(size_t)t * 4 + 0], x0);
  atomicAdd(&den[(size_t)t * 4 + 1], x1);
  atomicAdd(&den[(size_t)t * 4 + 2], x2);
  atomicAdd(&den[(size_t)t * 4 + 3], x3);
}

__global__ void k_init_bias(float* __restrict__ out, const float* __restrict__ bias, int n){
  int i = blockIdx.x * 256 + threadIdx.x;
  if (i < n) out[i] = bias[i & 127];
}

// out[t,d] += 0.25 * sum_h (cf[i,h]/den[t,h]) * hH[s, h*128+d]; 2 items per block.
__global__ void k_edge_agg(const int* __restrict__ src, const int* __restrict__ dst,
                           const float* __restrict__ cf, const float* __restrict__ den,
                           const float* __restrict__ hH, float* __restrict__ out,
                           int E_, int N_){
  int item = blockIdx.x * 2 + (threadIdx.x >> 7);
  if (item >= E_ + N_) return;
  int d = threadIdx.x & 127;
  int s, t;
  if (item < E_){ s = src[item]; t = dst[item]; } else { s = item - E_; t = s; }
  float4 c4 = *(const float4*)(cf + (size_t)item * 4);
  float4 d4 = *(const float4*)(den + (size_t)t * 4);
  float c0 = c4.x / d4.x, c1 = c4.y / d4.y, c2 = c4.z / d4.z, c3 = c4.w / d4.w;
  const float* hp = hH + (size_t)s * 512 + d;
  float v = 0.25f * (c0 * hp[0] + c1 * hp[128] + c2 * hp[256] + c3 * hp[384]);
  atomicAdd(&out[(size_t)t * DD + d], v);
}

__global__ void k_l2norm(float* __restrict__ X){
  int row  = blockIdx.x * 4 + (threadIdx.x >> 6);
  int lane = threadIdx.x & 63;
  float2 v = *(float2*)(X + (size_t)row * DD + lane * 2);
  float q = v.x * v.x + v.y * v.y;
  for (int o = 1; o < 64; o <<= 1) q += __shfl_xor(q, o);
  float sc = 1.0f / fmaxf(sqrtf(q), 1e-12f);
  v.x *= sc; v.y *= sc;
  *(float2*)(X + (size_t)row * DD + lane * 2) = v;
}

extern "C" void kernel_launch(void* const* d_in, const int* in_sizes, int n_in,
                              void* d_out, int out_size, void* d_ws, size_t ws_size,
                              hipStream_t stream){
  const float* x       = (const float*)d_in[0];
  const int*   ei      = (const int*)d_in[1];
  const int*   et      = (const int*)d_in[2];
  const float* r0_basis= (const float*)d_in[3];  const float* r0_comp = (const float*)d_in[4];
  const float* r0_root = (const float*)d_in[5];  const float* r0_bias = (const float*)d_in[6];
  const float* ln0_g   = (const float*)d_in[7];  const float* ln0_b   = (const float*)d_in[8];
  const float* r1_basis= (const float*)d_in[9];  const float* r1_comp = (const float*)d_in[10];
  const float* r1_root = (const float*)d_in[11]; const float* r1_bias = (const float*)d_in[12];
  const float* ln1_g   = (const float*)d_in[13]; const float* ln1_b   = (const float*)d_in[14];
  const float* gat_w   = (const float*)d_in[15]; const float* gat_asrc= (const float*)d_in[16];
  const float* gat_adst= (const float*)d_in[17]; const float* gat_bias= (const float*)d_in[18];
  const float* ln2_g   = (const float*)d_in[19]; const float* ln2_b   = (const float*)d_in[20];
  const float* r2_basis= (const float*)d_in[21]; const float* r2_comp = (const float*)d_in[22];
  const float* r2_root = (const float*)d_in[23]; const float* r2_bias = (const float*)d_in[24];

  const int N_ = in_sizes[0] / DD;
  const int E_ = in_sizes[2];
  const int* src = ei;
  const int* dst = ei + E_;
  float* T2 = (float*)d_out;

  char* wp_ = (char*)d_ws;
  auto alloc = [&](size_t b)->void*{ void* p = wp_; wp_ += (b + 255) & ~(size_t)255; return p; };
  float*    Wb  = (float*)   alloc((size_t)RR * DD * DD * 4);
  float*    inv = (float*)   alloc((size_t)RR * N_ * 4);
  float*    T1  = (float*)   alloc((size_t)N_ * DD * 4);
  float*    agg = (float*)   alloc((size_t)N_ * DD * 4);
  float*    hHb = (float*)   alloc((size_t)N_ * HH * DD * 4);
  float*    aS  = (float*)   alloc((size_t)N_ * HH * 4);
  float*    aD  = (float*)   alloc((size_t)N_ * HH * 4);
  unsigned* mx  = (unsigned*)alloc((size_t)N_ * HH * 4);
  float*    den = (float*)   alloc((size_t)N_ * HH * 4);
  float*    cf  = (float*)   alloc((size_t)(E_ + N_) * HH * 4);
  if ((size_t)(wp_ - (char*)d_ws) > ws_size) return;  // workspace too small: fail visibly

  // --- degrees per (relation,dst), once for all three RGCN layers ---
  hipMemsetAsync(inv, 0, (size_t)RR * N_ * 4, stream);
  k_deg  <<<(E_ + 255) / 256, 256, 0, stream>>>(et, dst, inv, E_, N_);
  k_recip<<<(RR * N_ + 255) / 256, 256, 0, stream>>>(inv, RR * N_);

  auto rgcn = [&](const float* xin, float* xout, const float* basis, const float* comp,
                  const float* root, const float* bias){
    k_make_W<<<512, 256, 0, stream>>>(basis, comp, Wb);
    k_gemm<<<dim3(N_ / 8, 1), 256, 0, stream>>>(xin, root, bias, nullptr, xout, DD, 0);
    for (int r = 0; r < RR; r++){
      hipMemsetAsync(agg, 0, (size_t)N_ * DD * 4, stream);
      k_scatter<<<(E_ + 1) / 2, 256, 0, stream>>>(src, dst, et, r, xin, agg, E_);
      k_gemm<<<dim3(N_ / 8, 1), 256, 0, stream>>>(agg, Wb + (size_t)r * DD * DD, nullptr,
                                                  inv + (size_t)r * N_, xout, DD, 1);
    }
  };

  // layer 0
  rgcn(x, T1, r0_basis, r0_comp, r0_root, r0_bias);
  k_ln_leaky<<<N_ / 4, 256, 0, stream>>>(T1, ln0_g, ln0_b, 0.1f);
  // layer 1
  rgcn(T1, T2, r1_basis, r1_comp, r1_root, r1_bias);
  k_ln_leaky<<<N_ / 4, 256, 0, stream>>>(T2, ln1_g, ln1_b, 0.1f);

  // --- GAT ---
  k_gemm<<<dim3(N_ / 8, 4), 256, 0, stream>>>(T2, gat_w, nullptr, nullptr, hHb, 512, 0);
  k_alpha<<<N_ / 4, 256, 0, stream>>>(hHb, gat_asrc, gat_adst, aS, aD);
  hipMemsetAsync(mx, 0, (size_t)N_ * HH * 4, stream);   // 0 == encf(-inf) identity
  k_edge_max<<<(E_ + N_ + 255) / 256, 256, 0, stream>>>(src, dst, aS, aD, mx, E_, N_);
  hipMemsetAsync(den, 0, (size_t)N_ * HH * 4, stream);
  k_edge_exp<<<(E_ + N_ + 255) / 256, 256, 0, stream>>>(src, dst, aS, aD, mx, den, cf, E_, N_);
  k_init_bias<<<(N_ * DD + 255) / 256, 256, 0, stream>>>(T1, gat_bias, N_ * DD);
  k_edge_agg<<<(E_ + N_ + 1) / 2, 256, 0, stream>>>(src, dst, cf, den, hHb, T1, E_, N_);
  k_ln_leaky<<<N_ / 4, 256, 0, stream>>>(T1, ln2_g, ln2_b, 0.1f);

  // layer 2 + final L2 normalize
  rgcn(T1, T2, r2_basis, r2_comp, r2_root, r2_bias);
  k_l2norm<<<N_ / 4, 256, 0, stream>>>(T2);
}

// Round 2
// 2516.023 us; speedup vs baseline: 15.7975x; 15.7975x over previous
//
#include <hip/hip_runtime.h>
#include <hip/hip_bf16.h>

#define RR 8
#define DD 128
#define HH 4

__device__ __forceinline__ unsigned encf(float f){
  unsigned u = __float_as_uint(f);
  return (u & 0x80000000u) ? ~u : (u | 0x80000000u);
}
__device__ __forceinline__ float decf(unsigned u){
  return (u & 0x80000000u) ? __uint_as_float(u & 0x7FFFFFFFu) : __uint_as_float(~u);
}
__device__ __forceinline__ float leaky(float x, float s){ return x > 0.f ? x : s * x; }

// Wcat[r*128+i][o] = sum_b comp[r,b]*basis[b,i,o]   (8*128*128 threads)
__global__ void k_make_W(const float* __restrict__ basis, const float* __restrict__ comp,
                         float* __restrict__ W){
  int idx = blockIdx.x * 256 + threadIdx.x;
  int r = idx >> 14, io = idx & 16383;
  float s = 0.f;
  #pragma unroll
  for (int b = 0; b < 8; b++) s += comp[r * 8 + b] * basis[b * 16384 + io];
  W[idx] = s;
}

__global__ void k_deg(const int* __restrict__ et, const int* __restrict__ dst,
                      float* __restrict__ deg, int E_, int N_){
  int e = blockIdx.x * 256 + threadIdx.x;
  if (e < E_) atomicAdd(&deg[(size_t)et[e] * N_ + dst[e]], 1.0f);
}

__global__ void k_recip(float* __restrict__ deg, int n){
  int i = blockIdx.x * 256 + threadIdx.x;
  if (i < n) deg[i] = 1.0f / fmaxf(deg[i], 1.0f);
}

// Tiled GEMM: C[M,ldc(+cb)] (=/+=) A[M,lda] * B[K,ldb(+cb)]  (+bias on init)
// Block = 256 thr -> 64 rows x 128 cols; thread = 8 rows x 4 cols.
#define FMA4(ac, s, b) { ac.x += (s)*(b).x; ac.y += (s)*(b).y; ac.z += (s)*(b).z; ac.w += (s)*(b).w; }
__launch_bounds__(256)
__global__ void k_gemm_t(const float* __restrict__ A, int lda, int M,
                         const float* __restrict__ B, int ldb,
                         const float* __restrict__ bias, int accumulate,
                         float* __restrict__ C, int ldc, int K){
  __shared__ float As[16][68];     // [k][m], padded
  __shared__ float Bs[16][128];    // [k][c]
  const int tid = threadIdx.x;
  const int m0  = blockIdx.x * 64;
  const int cb  = blockIdx.y << 7;
  // staging indices
  const int ar = tid >> 2;                 // 0..63 (A row within tile)
  const int ak = (tid & 3) << 2;           // 0,4,8,12
  const int bk = tid >> 5;                 // 0..7
  const int bc = (tid & 31) << 2;          // 0..124
  const int arow = min(m0 + ar, M - 1);
  const float* Ap = A + (size_t)arow * lda + ak;
  const float* Bp = B + (size_t)bk * ldb + cb + bc;
  // compute indices
  const int rg  = (tid >> 5) << 3;         // row group base 0..56
  const int col = (tid & 31) << 2;

  float4 acc[8];
  #pragma unroll
  for (int i = 0; i < 8; i++) acc[i] = make_float4(0.f, 0.f, 0.f, 0.f);

  float4 pa  = *(const float4*)Ap;
  float4 pb0 = *(const float4*)Bp;
  float4 pb1 = *(const float4*)(Bp + (size_t)8 * ldb);

  for (int k0 = 0; k0 < K; k0 += 16){
    As[ak + 0][ar] = pa.x; As[ak + 1][ar] = pa.y;
    As[ak + 2][ar] = pa.z; As[ak + 3][ar] = pa.w;
    *(float4*)&Bs[bk][bc]     = pb0;
    *(float4*)&Bs[bk + 8][bc] = pb1;
    __syncthreads();
    if (k0 + 16 < K){
      pa  = *(const float4*)(Ap + k0 + 16);
      pb0 = *(const float4*)(Bp + (size_t)(k0 + 16) * ldb);
      pb1 = *(const float4*)(Bp + (size_t)(k0 + 24) * ldb);
    }
    #pragma unroll
    for (int kk = 0; kk < 16; kk++){
      float4 b  = *(float4*)&Bs[kk][col];
      float4 a0 = *(float4*)&As[kk][rg];
      float4 a1 = *(float4*)&As[kk][rg + 4];
      FMA4(acc[0], a0.x, b); FMA4(acc[1], a0.y, b);
      FMA4(acc[2], a0.z, b); FMA4(acc[3], a0.w, b);
      FMA4(acc[4], a1.x, b); FMA4(acc[5], a1.y, b);
      FMA4(acc[6], a1.z, b); FMA4(acc[7], a1.w, b);
    }
    __syncthreads();
  }

  const int crow = m0 + rg;
  float* Cp = C + (size_t)crow * ldc + cb + col;
  #pragma unroll
  for (int i = 0; i < 8; i++){
    if (crow + i < M){
      float4 v = acc[i];
      float* p = Cp + (size_t)i * ldc;
      if (accumulate){
        float4 o = *(const float4*)p;
        v.x += o.x; v.y += o.y; v.z += o.z; v.w += o.w;
      } else if (bias){
        v.x += bias[col]; v.y += bias[col + 1]; v.z += bias[col + 2]; v.w += bias[col + 3];
      }
      *(float4*)p = v;
    }
  }
}

// agg[dst, (et-rbase)*128 + d] += inv[et,dst] * X[src,d]  for et in [rbase, rbase+4)
__global__ void k_scatter_g(const int* __restrict__ src, const int* __restrict__ dst,
                            const int* __restrict__ et, const float* __restrict__ inv,
                            const float* __restrict__ X, float* __restrict__ agg,
                            int E_, int N_, int rbase){
  int e = blockIdx.x * 2 + (threadIdx.x >> 7);
  if (e >= E_) return;
  int rl = et[e] - rbase;
  if ((unsigned)rl >= 4u) return;
  int t = dst[e];
  int d = threadIdx.x & 127;
  float w = inv[(size_t)(rbase + rl) * N_ + t];
  atomicAdd(&agg[(size_t)t * 512 + (rl << 7) + d], X[(size_t)src[e] * DD + d] * w);
}

// In-place LayerNorm over 128 feats + leaky_relu. One wave per row, 4 rows/block.
__global__ void k_ln_leaky(float* __restrict__ X, const float* __restrict__ g,
                           const float* __restrict__ b, float slope){
  int row  = blockIdx.x * 4 + (threadIdx.x >> 6);
  int lane = threadIdx.x & 63;
  float2 v = *(float2*)(X + (size_t)row * DD + lane * 2);
  float s = v.x + v.y;
  for (int o = 1; o < 64; o <<= 1) s += __shfl_xor(s, o);
  float mu = s * (1.f / 128.f);
  float dx = v.x - mu, dy = v.y - mu;
  float q = dx * dx + dy * dy;
  for (int o = 1; o < 64; o <<= 1) q += __shfl_xor(q, o);
  float rstd = rsqrtf(q * (1.f / 128.f) + 1e-5f);
  float2 gg = *(const float2*)(g + lane * 2), bb = *(const float2*)(b + lane * 2);
  float y0 = leaky(dx * rstd * gg.x + bb.x, slope);
  float y1 = leaky(dy * rstd * gg.y + bb.y, slope);
  *(float2*)(X + (size_t)row * DD + lane * 2) = make_float2(y0, y1);
}

// aS[n,h] = hH[n,h,:]·a_src[h,:], aD likewise. One wave per node (16 lanes/head).
__global__ void k_alpha(const float* __restrict__ hH, const float* __restrict__ a_src,
                        const float* __restrict__ a_dst, float* __restrict__ aS,
                        float* __restrict__ aD){
  int node = blockIdx.x * 4 + (threadIdx.x >> 6);
  int lane = threadIdx.x & 63;
  int h = lane >> 4, dgrp = lane & 15;
  const float4* p  = (const float4*)(hH + (size_t)node * 512 + h * 128 + dgrp * 8);
  const float4* s4 = (const float4*)(a_src + h * 128 + dgrp * 8);
  const float4* d4 = (const float4*)(a_dst + h * 128 + dgrp * 8);
  float4 v0 = p[0], v1 = p[1];
  float4 as0 = s4[0], as1 = s4[1], ad0 = d4[0], ad1 = d4[1];
  float ss = v0.x*as0.x + v0.y*as0.y + v0.z*as0.z + v0.w*as0.w
           + v1.x*as1.x + v1.y*as1.y + v1.z*as1.z + v1.w*as1.w;
  float sd = v0.x*ad0.x + v0.y*ad0.y + v0.z*ad0.z + v0.w*ad0.w
           + v1.x*ad1.x + v1.y*ad1.y + v1.z*ad1.z + v1.w*ad1.w;
  for (int o = 1; o < 16; o <<= 1){ ss += __shfl_xor(ss, o); sd += __shfl_xor(sd, o); }
  if (dgrp == 0){ aS[(size_t)node * 4 + h] = ss; aD[(size_t)node * 4 + h] = sd; }
}

// Items 0..E-1 are edges; E..E+N-1 are self loops.
__global__ void k_edge_max(const int* __restrict__ src, const int* __restrict__ dst,
                           const float* __restrict__ aS, const float* __restrict__ aD,
                           unsigned* __restrict__ mx, int E_, int N_){
  int i = blockIdx.x * 256 + threadIdx.x;
  if (i >= E_ + N_) return;
  int s, t;
  if (i < E_){ s = src[i]; t = dst[i]; } else { s = i - E_; t = s; }
  float4 a = *(const float4*)(aS + (size_t)s * 4);
  float4 b = *(const float4*)(aD + (size_t)t * 4);
  float e0 = leaky(a.x + b.x, 0.2f), e1 = leaky(a.y + b.y, 0.2f);
  float e2 = leaky(a.z + b.z, 0.2f), e3 = leaky(a.w + b.w, 0.2f);
  atomicMax(&mx[(size_t)t * 4 + 0], encf(e0));
  atomicMax(&mx[(size_t)t * 4 + 1], encf(e1));
  atomicMax(&mx[(size_t)t * 4 + 2], encf(e2));
  atomicMax(&mx[(size_t)t * 4 + 3], encf(e3));
}

__global__ void k_edge_exp(const int* __restrict__ src, const int* __restrict__ dst,
                           const float* __restrict__ aS, const float* __restrict__ aD,
                           const unsigned* __restrict__ mx, float* __restrict__ den,
                           float* __restrict__ cf, int E_, int N_){
  int i = blockIdx.x * 256 + threadIdx.x;
  if (i >= E_ + N_) return;
  int s, t;
  if (i < E_){ s = src[i]; t = dst[i]; } else { s = i - E_; t = s; }
  float4 a = *(const float4*)(aS + (size_t)s * 4);
  float4 b = *(const float4*)(aD + (size_t)t * 4);
  float e0 = leaky(a.x + b.x, 0.2f), e1 = leaky(a.y + b.y, 0.2f);
  float e2 = leaky(a.z + b.z, 0.2f), e3 = leaky(a.w + b.w, 0.2f);
  float x0 = expf(e0 - decf(mx[(size_t)t * 4 + 0]));
  float x1 = expf(e1 - decf(mx[(size_t)t * 4 + 1]));
  float x2 = expf(e2 - decf(mx[(size_t)t * 4 + 2]));
  float x3 = expf(e3 - decf(mx[(size_t)t * 4 + 3]));
  *(float4*)(cf + (size_t)i * 4) = make_float4(x0, x1, x2, x3);
  atomicAdd(&den[(size_t)t * 4 + 0], x0);
  atomicAdd(&den[(size_t)t * 4 + 1], x1);
  atomicAdd(&den[(size_t)t * 4 + 2], x2);
  atomicAdd(&den[(size_t)t * 4 + 3], x3);
}

__global__ void k_init_bias(float* __restrict__ out, const float* __restrict__ bias, int n){
  int i = blockIdx.x * 256 + threadIdx.x;
  if (i < n) out[i] = bias[i & 127];
}

// out[t,d] += 0.25 * sum_h (cf[i,h]/den[t,h]) * hH[s, h*128+d]; 2 items per block.
__global__ void k_edge_agg(const int* __restrict__ src, const int* __restrict__ dst,
                           const float* __restrict__ cf, const float* __restrict__ den,
                           const float* __restrict__ hH, float* __restrict__ out,
                           int E_, int N_){
  int item = blockIdx.x * 2 + (threadIdx.x >> 7);
  if (item >= E_ + N_) return;
  int d = threadIdx.x & 127;
  int s, t;
  if (item < E_){ s = src[item]; t = dst[item]; } else { s = item - E_; t = s; }
  float4 c4 = *(const float4*)(cf + (size_t)item * 4);
  float4 d4 = *(const float4*)(den + (size_t)t * 4);
  float c0 = c4.x / d4.x, c1 = c4.y / d4.y, c2 = c4.z / d4.z, c3 = c4.w / d4.w;
  const float* hp = hH + (size_t)s * 512 + d;
  float v = 0.25f * (c0 * hp[0] + c1 * hp[128] + c2 * hp[256] + c3 * hp[384]);
  atomicAdd(&out[(size_t)t * DD + d], v);
}

__global__ void k_l2norm(float* __restrict__ X){
  int row  = blockIdx.x * 4 + (threadIdx.x >> 6);
  int lane = threadIdx.x & 63;
  float2 v = *(float2*)(X + (size_t)row * DD + lane * 2);
  float q = v.x * v.x + v.y * v.y;
  for (int o = 1; o < 64; o <<= 1) q += __shfl_xor(q, o);
  float sc = 1.0f / fmaxf(sqrtf(q), 1e-12f);
  v.x *= sc; v.y *= sc;
  *(float2*)(X + (size_t)row * DD + lane * 2) = v;
}

extern "C" void kernel_launch(void* const* d_in, const int* in_sizes, int n_in,
                              void* d_out, int out_size, void* d_ws, size_t ws_size,
                              hipStream_t stream){
  const float* x       = (const float*)d_in[0];
  const int*   ei      = (const int*)d_in[1];
  const int*   et      = (const int*)d_in[2];
  const float* r0_basis= (const float*)d_in[3];  const float* r0_comp = (const float*)d_in[4];
  const float* r0_root = (const float*)d_in[5];  const float* r0_bias = (const float*)d_in[6];
  const float* ln0_g   = (const float*)d_in[7];  const float* ln0_b   = (const float*)d_in[8];
  const float* r1_basis= (const float*)d_in[9];  const float* r1_comp = (const float*)d_in[10];
  const float* r1_root = (const float*)d_in[11]; const float* r1_bias = (const float*)d_in[12];
  const float* ln1_g   = (const float*)d_in[13]; const float* ln1_b   = (const float*)d_in[14];
  const float* gat_w   = (const float*)d_in[15]; const float* gat_asrc= (const float*)d_in[16];
  const float* gat_adst= (const float*)d_in[17]; const float* gat_bias= (const float*)d_in[18];
  const float* ln2_g   = (const float*)d_in[19]; const float* ln2_b   = (const float*)d_in[20];
  const float* r2_basis= (const float*)d_in[21]; const float* r2_comp = (const float*)d_in[22];
  const float* r2_root = (const float*)d_in[23]; const float* r2_bias = (const float*)d_in[24];

  const int N_ = in_sizes[0] / DD;
  const int E_ = in_sizes[2];
  const int Npad = (N_ + 63) & ~63;
  const int* src = ei;
  const int* dst = ei + E_;
  float* T2 = (float*)d_out;

  char* wp_ = (char*)d_ws;
  auto alloc = [&](size_t b)->void*{ void* p = wp_; wp_ += (b + 255) & ~(size_t)255; return p; };
  float*    Wcat = (float*)   alloc((size_t)RR * DD * DD * 4);
  float*    inv  = (float*)   alloc((size_t)RR * N_ * 4);
  float*    T1   = (float*)   alloc((size_t)N_ * DD * 4);
  float*    shrd = (float*)   alloc((size_t)Npad * 512 * 4);   // agg (RGCN) / hH (GAT)
  float*    aS   = (float*)   alloc((size_t)N_ * HH * 4);
  float*    aD   = (float*)   alloc((size_t)N_ * HH * 4);
  unsigned* mx   = (unsigned*)alloc((size_t)N_ * HH * 4);
  float*    den  = (float*)   alloc((size_t)N_ * HH * 4);
  float*    cf   = (float*)   alloc((size_t)(E_ + N_) * HH * 4);
  if ((size_t)(wp_ - (char*)d_ws) > ws_size) return;  // workspace too small: fail visibly
  float* agg = shrd;
  float* hHb = shrd;

  const int Mb = (N_ + 63) / 64;

  // --- degrees per (relation,dst), once for all three RGCN layers ---
  hipMemsetAsync(inv, 0, (size_t)RR * N_ * 4, stream);
  k_deg  <<<(E_ + 255) / 256, 256, 0, stream>>>(et, dst, inv, E_, N_);
  k_recip<<<(RR * N_ + 255) / 256, 256, 0, stream>>>(inv, RR * N_);

  auto rgcn = [&](const float* xin, float* xout, const float* basis, const float* comp,
                  const float* root, const float* bias){
    k_make_W<<<512, 256, 0, stream>>>(basis, comp, Wcat);
    // root part (init with bias)
    k_gemm_t<<<dim3(Mb, 1), 256, 0, stream>>>(xin, DD, N_, root, DD, bias, 0, xout, DD, DD);
    // relation groups 0..3 and 4..7, K=512 each
    for (int g = 0; g < 2; g++){
      hipMemsetAsync(agg, 0, (size_t)Npad * 512 * 4, stream);
      k_scatter_g<<<(E_ + 1) / 2, 256, 0, stream>>>(src, dst, et, inv, xin, agg, E_, N_, g * 4);
      k_gemm_t<<<dim3(Mb, 1), 256, 0, stream>>>(agg, 512, N_, Wcat + (size_t)g * 4 * DD * DD,
                                                DD, nullptr, 1, xout, DD, 512);
    }
  };

  // layer 0
  rgcn(x, T1, r0_basis, r0_comp, r0_root, r0_bias);
  k_ln_leaky<<<N_ / 4, 256, 0, stream>>>(T1, ln0_g, ln0_b, 0.1f);
  // layer 1
  rgcn(T1, T2, r1_basis, r1_comp, r1_root, r1_bias);
  k_ln_leaky<<<N_ / 4, 256, 0, stream>>>(T2, ln1_g, ln1_b, 0.1f);

  // --- GAT ---
  k_gemm_t<<<dim3(Mb, 4), 256, 0, stream>>>(T2, DD, N_, gat_w, 512, nullptr, 0, hHb, 512, DD);
  k_alpha<<<N_ / 4, 256, 0, stream>>>(hHb, gat_asrc, gat_adst, aS, aD);
  hipMemsetAsync(mx, 0, (size_t)N_ * HH * 4, stream);
  k_edge_max<<<(E_ + N_ + 255) / 256, 256, 0, stream>>>(src, dst, aS, aD, mx, E_, N_);
  hipMemsetAsync(den, 0, (size_t)N_ * HH * 4, stream);
  k_edge_exp<<<(E_ + N_ + 255) / 256, 256, 0, stream>>>(src, dst, aS, aD, mx, den, cf, E_, N_);
  k_init_bias<<<(N_ * DD + 255) / 256, 256, 0, stream>>>(T1, gat_bias, N_ * DD);
  k_edge_agg<<<(E_ + N_ + 1) / 2, 256, 0, stream>>>(src, dst, cf, den, hHb, T1, E_, N_);
  k_ln_leaky<<<N_ / 4, 256, 0, stream>>>(T1, ln2_g, ln2_b, 0.1f);

  // layer 2 + final L2 normalize
  rgcn(T1, T2, r2_basis, r2_comp, r2_root, r2_bias);
  k_l2norm<<<N_ / 4, 256, 0, stream>>>(T2);
}

// Round 3
// 724.020 us; speedup vs baseline: 54.8975x; 3.4751x over previous
//
#include <hip/hip_runtime.h>
#include <hip/hip_bf16.h>

#define DD 128
#define NKEY8 8   // keys per dst = R

using bf16x8 = __attribute__((ext_vector_type(8))) __bf16;
using f32x4  = __attribute__((ext_vector_type(4))) float;

__device__ __forceinline__ float leaky(float x, float s){ return x > 0.f ? x : s * x; }

// ---------------- CSR build (counting sort by key = dst*8 + etype) ----------------
__global__ void k_hist(const int* __restrict__ dst, const int* __restrict__ et,
                       int* __restrict__ cnt, int E_){
  int e = blockIdx.x * 256 + threadIdx.x;
  if (e < E_) atomicAdd(&cnt[dst[e] * NKEY8 + et[e]], 1);
}

// block scans 1024 items (256 thr x 4), writes per-block exclusive scan + block sum
__global__ void k_scan1(const int* __restrict__ cnt, int* __restrict__ ptr,
                        int* __restrict__ part, int n){
  __shared__ int sm[256];
  int tid = threadIdx.x;
  int base = blockIdx.x * 1024 + tid * 4;
  int a0 = base + 0 < n ? cnt[base + 0] : 0;
  int a1 = base + 1 < n ? cnt[base + 1] : 0;
  int a2 = base + 2 < n ? cnt[base + 2] : 0;
  int a3 = base + 3 < n ? cnt[base + 3] : 0;
  int s = a0 + a1 + a2 + a3;
  sm[tid] = s; __syncthreads();
  for (int off = 1; off < 256; off <<= 1){
    int v = tid >= off ? sm[tid - off] : 0;
    __syncthreads(); sm[tid] += v; __syncthreads();
  }
  int ex = sm[tid] - s;
  if (tid == 255) part[blockIdx.x] = sm[255];
  if (base + 0 < n) ptr[base + 0] = ex;
  if (base + 1 < n) ptr[base + 1] = ex + a0;
  if (base + 2 < n) ptr[base + 2] = ex + a0 + a1;
  if (base + 3 < n) ptr[base + 3] = ex + a0 + a1 + a2;
}

__global__ void k_scan2(int* __restrict__ part, int nb){  // single block, 512 thr
  __shared__ int sm[512];
  int tid = threadIdx.x;
  int v = tid < nb ? part[tid] : 0;
  sm[tid] = v; __syncthreads();
  for (int off = 1; off < 512; off <<= 1){
    int u = tid >= off ? sm[tid - off] : 0;
    __syncthreads(); sm[tid] += u; __syncthreads();
  }
  if (tid < nb) part[tid] = sm[tid] - v;  // exclusive
}

__global__ void k_scan3(int* __restrict__ ptr, const int* __restrict__ part, int n, int E_){
  int i = blockIdx.x * 256 + threadIdx.x;
  if (i < n) ptr[i] += part[i >> 10];
  if (i == n) ptr[n] = E_;
}

__global__ void k_inv(const int* __restrict__ ptr, float* __restrict__ inv, int n){
  int i = blockIdx.x * 256 + threadIdx.x;
  if (i < n) inv[i] = 1.0f / fmaxf((float)(ptr[i + 1] - ptr[i]), 1.0f);
}

__global__ void k_scatter_pos(const int* __restrict__ src, const int* __restrict__ dst,
                              const int* __restrict__ et, int* __restrict__ run,
                              int* __restrict__ esrc, int E_){
  int e = blockIdx.x * 256 + threadIdx.x;
  if (e >= E_) return;
  int pos = atomicAdd(&run[dst[e] * NKEY8 + et[e]], 1);
  esrc[pos] = src[e];
}

__global__ void k_cvt(const float* __restrict__ in, __hip_bfloat16* __restrict__ out, int n){
  int i = blockIdx.x * 256 + threadIdx.x;
  if (i < n) out[i] = __float2bfloat16(in[i]);
}

// ---------------- weights: combine + pack into MFMA B-fragment order ----------------
// B-frag layout for v_mfma_f32_16x16x32_bf16: n = lane&15, k = (lane>>4)*8 + i
// packed offset = ((k_tile*NT + n_tile)*64 + lane)*8 + i
__global__ void k_makeW(const float* __restrict__ basis, const float* __restrict__ comp,
                        const float* __restrict__ root, __hip_bfloat16* __restrict__ Wp){
  int idx = blockIdx.x * 256 + threadIdx.x;   // k*128 + n, k in [0,1152)
  int k = idx >> 7, n = idx & 127;
  float v;
  if (k < 1024){
    int r = k >> 7, i = k & 127;
    float s = 0.f;
    #pragma unroll
    for (int b = 0; b < 8; b++) s += comp[r * 8 + b] * basis[b * 16384 + i * 128 + n];
    v = s;
  } else {
    v = root[(k - 1024) * 128 + n];
  }
  int kt = k >> 5, kr = k & 31;
  int lane = (n & 15) | ((kr >> 3) << 4);
  int ii = kr & 7, nt = n >> 4;
  Wp[((size_t)(kt * 8 + nt) * 64 + lane) * 8 + ii] = __float2bfloat16(v);
}

__global__ void k_packG(const float* __restrict__ Wg, __hip_bfloat16* __restrict__ Wp){
  int idx = blockIdx.x * 256 + threadIdx.x;   // k*512 + n, k in [0,128)
  int k = idx >> 9, n = idx & 511;
  int kt = k >> 5, kr = k & 31;
  int lane = (n & 15) | ((kr >> 3) << 4);
  int ii = kr & 7, nt = n >> 4;
  Wp[((size_t)(kt * 32 + nt) * 64 + lane) * 8 + ii] = __float2bfloat16(Wg[idx]);
}

// ---------------- RGCN: CSR aggregation into bf16 [N, 1152] ----------------
__global__ void k_csr_agg(const int* __restrict__ ptr, const int* __restrict__ esrc,
                          const float* __restrict__ inv, const __hip_bfloat16* __restrict__ xb,
                          __hip_bfloat16* __restrict__ agg){
  int t = blockIdx.x, d = threadIdx.x;
  size_t ob = (size_t)t * 1152;
  #pragma unroll 1
  for (int r = 0; r < 8; r++){
    int beg = ptr[t * 8 + r], end = ptr[t * 8 + r + 1];
    float acc = 0.f;
    for (int e = beg; e < end; e++)
      acc += __bfloat162float(xb[(size_t)esrc[e] * DD + d]);
    agg[ob + r * 128 + d] = __float2bfloat16(acc * inv[t * 8 + r]);
  }
  agg[ob + 1024 + d] = xb[(size_t)t * DD + d];
}

// ---------------- MFMA GEMM: C[M,ldc] = A16[M,K] * Bpacked + bias ----------------
// A-frag: m = lane&15, k = (lane>>4)*8+i (16B contiguous per lane, direct global load)
// C/D:    col = lane&15, row = (lane>>4)*4 + j   [guide-verified]
__launch_bounds__(256)
__global__ void k_gemm_mfma(const __hip_bfloat16* __restrict__ A, int lda, int M,
                            const __hip_bfloat16* __restrict__ Bp, int ntt,
                            const float* __restrict__ bias,
                            float* __restrict__ Cf, __hip_bfloat16* __restrict__ Cb,
                            int ldc, int K){
  int wave = threadIdx.x >> 6, lane = threadIdx.x & 63;
  int nt0 = blockIdx.y << 3;
  int mbase = blockIdx.x * 128 + wave * 32;
  int r0 = min(mbase + (lane & 15), M - 1);
  int r1 = min(mbase + 16 + (lane & 15), M - 1);
  const __hip_bfloat16* a0p = A + (size_t)r0 * lda + ((lane >> 4) << 3);
  const __hip_bfloat16* a1p = A + (size_t)r1 * lda + ((lane >> 4) << 3);
  f32x4 acc[2][8];
  #pragma unroll
  for (int i = 0; i < 2; i++)
    #pragma unroll
    for (int j = 0; j < 8; j++) acc[i][j] = (f32x4){0.f, 0.f, 0.f, 0.f};

  for (int k0 = 0; k0 < K; k0 += 32){
    bf16x8 a0 = *(const bf16x8*)a0p; a0p += 32;
    bf16x8 a1 = *(const bf16x8*)a1p; a1p += 32;
    const bf16x8* bfr = (const bf16x8*)(Bp + (((size_t)(k0 >> 5) * ntt + nt0) * 64 + lane) * 8);
    #pragma unroll
    for (int nt = 0; nt < 8; nt++){
      bf16x8 b = bfr[(size_t)nt * 64];
      acc[0][nt] = __builtin_amdgcn_mfma_f32_16x16x32_bf16(a0, b, acc[0][nt], 0, 0, 0);
      acc[1][nt] = __builtin_amdgcn_mfma_f32_16x16x32_bf16(a1, b, acc[1][nt], 0, 0, 0);
    }
  }
  int colb = lane & 15;
  int rg = (lane >> 4) << 2;
  #pragma unroll
  for (int mt = 0; mt < 2; mt++){
    int rowb = mbase + mt * 16 + rg;
    #pragma unroll
    for (int nt = 0; nt < 8; nt++){
      int col = ((nt0 + nt) << 4) + colb;
      float bv = bias ? bias[col & 127] : 0.f;
      #pragma unroll
      for (int j = 0; j < 4; j++){
        int row = rowb + j;
        if (row < M){
          float v = acc[mt][nt][j] + bv;
          if (Cf) Cf[(size_t)row * ldc + col] = v;
          else    Cb[(size_t)row * ldc + col] = __float2bfloat16(v);
        }
      }
    }
  }
}

// ---------------- LayerNorm + leaky, fp32 in -> bf16 out ----------------
__global__ void k_ln_leaky(const float* __restrict__ X, const float* __restrict__ g,
                           const float* __restrict__ b, __hip_bfloat16* __restrict__ out,
                           float slope){
  int row  = blockIdx.x * 4 + (threadIdx.x >> 6);
  int lane = threadIdx.x & 63;
  float2 v = *(const float2*)(X + (size_t)row * DD + lane * 2);
  float s = v.x + v.y;
  for (int o = 1; o < 64; o <<= 1) s += __shfl_xor(s, o);
  float mu = s * (1.f / 128.f);
  float dx = v.x - mu, dy = v.y - mu;
  float q = dx * dx + dy * dy;
  for (int o = 1; o < 64; o <<= 1) q += __shfl_xor(q, o);
  float rstd = rsqrtf(q * (1.f / 128.f) + 1e-5f);
  float2 gg = *(const float2*)(g + lane * 2), bb = *(const float2*)(b + lane * 2);
  float y0 = leaky(dx * rstd * gg.x + bb.x, slope);
  float y1 = leaky(dy * rstd * gg.y + bb.y, slope);
  __hip_bfloat162 o2;
  o2.x = __float2bfloat16(y0); o2.y = __float2bfloat16(y1);
  *(__hip_bfloat162*)(out + (size_t)row * DD + lane * 2) = o2;
}

// ---------------- GAT: alpha dots from bf16 hH ----------------
__global__ void k_alpha(const __hip_bfloat16* __restrict__ hH, const float* __restrict__ a_src,
                        const float* __restrict__ a_dst, float* __restrict__ aS,
                        float* __restrict__ aD){
  int node = blockIdx.x * 4 + (threadIdx.x >> 6);
  int lane = threadIdx.x & 63;
  int h = lane >> 4, dg = lane & 15;
  uint4 u = *(const uint4*)(hH + (size_t)node * 512 + h * 128 + dg * 8);
  const float* as = a_src + h * 128 + dg * 8;
  const float* ad = a_dst + h * 128 + dg * 8;
  float ss = 0.f, sd = 0.f;
  #pragma unroll
  for (int w = 0; w < 4; w++){
    unsigned uw = ((const unsigned*)&u)[w];
    float f0 = __uint_as_float(uw << 16);
    float f1 = __uint_as_float(uw & 0xffff0000u);
    ss += f0 * as[w * 2] + f1 * as[w * 2 + 1];
    sd += f0 * ad[w * 2] + f1 * ad[w * 2 + 1];
  }
  for (int o = 1; o < 16; o <<= 1){ ss += __shfl_xor(ss, o); sd += __shfl_xor(sd, o); }
  if (dg == 0){ aS[(size_t)node * 4 + h] = ss; aD[(size_t)node * 4 + h] = sd; }
}

// ---------------- GAT fused: per-dst softmax + aggregation + head mean + bias ----------------
__global__ void k_gat_fused(const int* __restrict__ ptr, const int* __restrict__ esrc,
                            const float* __restrict__ aS, const float* __restrict__ aD,
                            const __hip_bfloat16* __restrict__ hH,
                            const float* __restrict__ bias, float* __restrict__ out){
  int t = blockIdx.x, d = threadIdx.x;
  int beg = ptr[t * 8], end = ptr[t * 8 + 8];
  float4 adt = *(const float4*)(aD + (size_t)t * 4);
  float4 ast = *(const float4*)(aS + (size_t)t * 4);
  // phase 1: max over edges + self loop
  float m0 = leaky(ast.x + adt.x, 0.2f), m1 = leaky(ast.y + adt.y, 0.2f);
  float m2 = leaky(ast.z + adt.z, 0.2f), m3 = leaky(ast.w + adt.w, 0.2f);
  for (int e = beg; e < end; e++){
    int s = esrc[e];
    float4 a = *(const float4*)(aS + (size_t)s * 4);
    m0 = fmaxf(m0, leaky(a.x + adt.x, 0.2f));
    m1 = fmaxf(m1, leaky(a.y + adt.y, 0.2f));
    m2 = fmaxf(m2, leaky(a.z + adt.z, 0.2f));
    m3 = fmaxf(m3, leaky(a.w + adt.w, 0.2f));
  }
  // phase 2: exp-sum + weighted aggregation (self loop first)
  float x0 = __expf(leaky(ast.x + adt.x, 0.2f) - m0);
  float x1 = __expf(leaky(ast.y + adt.y, 0.2f) - m1);
  float x2 = __expf(leaky(ast.z + adt.z, 0.2f) - m2);
  float x3 = __expf(leaky(ast.w + adt.w, 0.2f) - m3);
  float den0 = x0, den1 = x1, den2 = x2, den3 = x3;
  const __hip_bfloat16* hp = hH + (size_t)t * 512 + d;
  float ac0 = x0 * __bfloat162float(hp[0]);
  float ac1 = x1 * __bfloat162float(hp[128]);
  float ac2 = x2 * __bfloat162float(hp[256]);
  float ac3 = x3 * __bfloat162float(hp[384]);
  for (int e = beg; e < end; e++){
    int s = esrc[e];
    float4 a = *(const float4*)(aS + (size_t)s * 4);
    float e0 = __expf(leaky(a.x + adt.x, 0.2f) - m0);
    float e1 = __expf(leaky(a.y + adt.y, 0.2f) - m1);
    float e2 = __expf(leaky(a.z + adt.z, 0.2f) - m2);
    float e3 = __expf(leaky(a.w + adt.w, 0.2f) - m3);
    den0 += e0; den1 += e1; den2 += e2; den3 += e3;
    const __hip_bfloat16* sp = hH + (size_t)s * 512 + d;
    ac0 += e0 * __bfloat162float(sp[0]);
    ac1 += e1 * __bfloat162float(sp[128]);
    ac2 += e2 * __bfloat162float(sp[256]);
    ac3 += e3 * __bfloat162float(sp[384]);
  }
  out[(size_t)t * DD + d] = 0.25f * (ac0 / den0 + ac1 / den1 + ac2 / den2 + ac3 / den3) + bias[d];
}

__global__ void k_l2norm(float* __restrict__ X){
  int row  = blockIdx.x * 4 + (threadIdx.x >> 6);
  int lane = threadIdx.x & 63;
  float2 v = *(float2*)(X + (size_t)row * DD + lane * 2);
  float q = v.x * v.x + v.y * v.y;
  for (int o = 1; o < 64; o <<= 1) q += __shfl_xor(q, o);
  float sc = 1.0f / fmaxf(sqrtf(q), 1e-12f);
  v.x *= sc; v.y *= sc;
  *(float2*)(X + (size_t)row * DD + lane * 2) = v;
}

extern "C" void kernel_launch(void* const* d_in, const int* in_sizes, int n_in,
                              void* d_out, int out_size, void* d_ws, size_t ws_size,
                              hipStream_t stream){
  const float* x       = (const float*)d_in[0];
  const int*   ei      = (const int*)d_in[1];
  const int*   et      = (const int*)d_in[2];
  const float* r0_basis= (const float*)d_in[3];  const float* r0_comp = (const float*)d_in[4];
  const float* r0_root = (const float*)d_in[5];  const float* r0_bias = (const float*)d_in[6];
  const float* ln0_g   = (const float*)d_in[7];  const float* ln0_b   = (const float*)d_in[8];
  const float* r1_basis= (const float*)d_in[9];  const float* r1_comp = (const float*)d_in[10];
  const float* r1_root = (const float*)d_in[11]; const float* r1_bias = (const float*)d_in[12];
  const float* ln1_g   = (const float*)d_in[13]; const float* ln1_b   = (const float*)d_in[14];
  const float* gat_w   = (const float*)d_in[15]; const float* gat_asrc= (const float*)d_in[16];
  const float* gat_adst= (const float*)d_in[17]; const float* gat_bias= (const float*)d_in[18];
  const float* ln2_g   = (const float*)d_in[19]; const float* ln2_b   = (const float*)d_in[20];
  const float* r2_basis= (const float*)d_in[21]; const float* r2_comp = (const float*)d_in[22];
  const float* r2_root = (const float*)d_in[23]; const float* r2_bias = (const float*)d_in[24];

  const int N_ = in_sizes[0] / DD;
  const int E_ = in_sizes[2];
  const int NK = N_ * NKEY8;
  const int* src = ei;
  const int* dst = ei + E_;
  float* T2 = (float*)d_out;

  char* wp_ = (char*)d_ws;
  auto alloc = [&](size_t b)->void*{ void* p = wp_; wp_ += (b + 255) & ~(size_t)255; return p; };
  __hip_bfloat16* agg16 = (__hip_bfloat16*)alloc((size_t)N_ * 1152 * 2);  // also hosts hH16
  __hip_bfloat16* xb16  = (__hip_bfloat16*)alloc((size_t)N_ * DD * 2);
  float*          T1    = (float*)alloc((size_t)N_ * DD * 4);
  float*          inv   = (float*)alloc((size_t)NK * 4);
  int*            ptrb  = (int*)alloc((size_t)(NK + 1) * 4);
  int*            cnt   = (int*)alloc((size_t)NK * 4);
  int*            run   = (int*)alloc((size_t)NK * 4);
  int*            esrc  = (int*)alloc((size_t)E_ * 4);
  int*            part  = (int*)alloc(512 * 4);
  float*          aS    = (float*)alloc((size_t)N_ * 4 * 4);
  float*          aD    = (float*)alloc((size_t)N_ * 4 * 4);
  __hip_bfloat16* Wp    = (__hip_bfloat16*)alloc((size_t)1152 * 128 * 2);
  __hip_bfloat16* WpG   = (__hip_bfloat16*)alloc((size_t)128 * 512 * 2);
  if ((size_t)(wp_ - (char*)d_ws) > ws_size) return;
  __hip_bfloat16* hH16 = agg16;

  const int Mb = (N_ + 127) / 128;
  const int nScanB = (NK + 1023) / 1024;

  // ---- CSR build (once; same graph for all layers) ----
  hipMemsetAsync(cnt, 0, (size_t)NK * 4, stream);
  k_hist<<<(E_ + 255) / 256, 256, 0, stream>>>(dst, et, cnt, E_);
  k_scan1<<<nScanB, 256, 0, stream>>>(cnt, ptrb, part, NK);
  k_scan2<<<1, 512, 0, stream>>>(part, nScanB);
  k_scan3<<<(NK + 1 + 255) / 256, 256, 0, stream>>>(ptrb, part, NK, E_);
  k_inv<<<(NK + 255) / 256, 256, 0, stream>>>(ptrb, inv, NK);
  hipMemcpyAsync(run, ptrb, (size_t)NK * 4, hipMemcpyDeviceToDevice, stream);
  k_scatter_pos<<<(E_ + 255) / 256, 256, 0, stream>>>(src, dst, et, run, esrc, E_);
  k_cvt<<<(N_ * DD + 255) / 256, 256, 0, stream>>>(x, xb16, N_ * DD);

  auto rgcn = [&](const float* basis, const float* comp, const float* root,
                  const float* bias, float* xout){
    k_makeW<<<576, 256, 0, stream>>>(basis, comp, root, Wp);
    k_csr_agg<<<N_, 128, 0, stream>>>(ptrb, esrc, inv, xb16, agg16);
    k_gemm_mfma<<<dim3(Mb, 1), 256, 0, stream>>>(agg16, 1152, N_, Wp, 8, bias,
                                                 xout, nullptr, DD, 1152);
  };

  // layer 0
  rgcn(r0_basis, r0_comp, r0_root, r0_bias, T1);
  k_ln_leaky<<<N_ / 4, 256, 0, stream>>>(T1, ln0_g, ln0_b, xb16, 0.1f);
  // layer 1
  rgcn(r1_basis, r1_comp, r1_root, r1_bias, T1);
  k_ln_leaky<<<N_ / 4, 256, 0, stream>>>(T1, ln1_g, ln1_b, xb16, 0.1f);

  // ---- GAT ----
  k_packG<<<256, 256, 0, stream>>>(gat_w, WpG);
  k_gemm_mfma<<<dim3(Mb, 4), 256, 0, stream>>>(xb16, DD, N_, WpG, 32, nullptr,
                                               nullptr, hH16, 512, DD);
  k_alpha<<<N_ / 4, 256, 0, stream>>>(hH16, gat_asrc, gat_adst, aS, aD);
  k_gat_fused<<<N_, 128, 0, stream>>>(ptrb, esrc, aS, aD, hH16, gat_bias, T1);
  k_ln_leaky<<<N_ / 4, 256, 0, stream>>>(T1, ln2_g, ln2_b, xb16, 0.1f);

  // layer 2 -> d_out, then L2 normalize
  rgcn(r2_basis, r2_comp, r2_root, r2_bias, T2);
  k_l2norm<<<N_ / 4, 256, 0, stream>>>(T2);
}

// Round 4
// 627.554 us; speedup vs baseline: 63.3362x; 1.1537x over previous
//
#include <hip/hip_runtime.h>
#include <hip/hip_bf16.h>

#define DD 128
#define NKEY8 8   // keys per dst = R

using bf16x8 = __attribute__((ext_vector_type(8))) __bf16;
using f32x4  = __attribute__((ext_vector_type(4))) float;

__device__ __forceinline__ float leaky(float x, float s){ return x > 0.f ? x : s * x; }

// ---------------- CSR build (counting sort by key = dst*8 + etype) ----------------
__global__ void k_hist(const int* __restrict__ dst, const int* __restrict__ et,
                       int* __restrict__ cnt, int E_){
  int e = blockIdx.x * 256 + threadIdx.x;
  if (e < E_) atomicAdd(&cnt[dst[e] * NKEY8 + et[e]], 1);
}

__global__ void k_scan1(const int* __restrict__ cnt, int* __restrict__ ptr,
                        int* __restrict__ part, int n){
  __shared__ int sm[256];
  int tid = threadIdx.x;
  int base = blockIdx.x * 1024 + tid * 4;
  int a0 = base + 0 < n ? cnt[base + 0] : 0;
  int a1 = base + 1 < n ? cnt[base + 1] : 0;
  int a2 = base + 2 < n ? cnt[base + 2] : 0;
  int a3 = base + 3 < n ? cnt[base + 3] : 0;
  int s = a0 + a1 + a2 + a3;
  sm[tid] = s; __syncthreads();
  for (int off = 1; off < 256; off <<= 1){
    int v = tid >= off ? sm[tid - off] : 0;
    __syncthreads(); sm[tid] += v; __syncthreads();
  }
  int ex = sm[tid] - s;
  if (tid == 255) part[blockIdx.x] = sm[255];
  if (base + 0 < n) ptr[base + 0] = ex;
  if (base + 1 < n) ptr[base + 1] = ex + a0;
  if (base + 2 < n) ptr[base + 2] = ex + a0 + a1;
  if (base + 3 < n) ptr[base + 3] = ex + a0 + a1 + a2;
}

__global__ void k_scan2(int* __restrict__ part, int nb){  // single block, 512 thr
  __shared__ int sm[512];
  int tid = threadIdx.x;
  int v = tid < nb ? part[tid] : 0;
  sm[tid] = v; __syncthreads();
  for (int off = 1; off < 512; off <<= 1){
    int u = tid >= off ? sm[tid - off] : 0;
    __syncthreads(); sm[tid] += u; __syncthreads();
  }
  if (tid < nb) part[tid] = sm[tid] - v;  // exclusive
}

__global__ void k_scan3(int* __restrict__ ptr, const int* __restrict__ part, int n, int E_){
  int i = blockIdx.x * 256 + threadIdx.x;
  if (i < n) ptr[i] += part[i >> 10];
  if (i == n) ptr[n] = E_;
}

__global__ void k_inv(const int* __restrict__ ptr, float* __restrict__ inv, int n){
  int i = blockIdx.x * 256 + threadIdx.x;
  if (i < n) inv[i] = 1.0f / fmaxf((float)(ptr[i + 1] - ptr[i]), 1.0f);
}

__global__ void k_scatter_pos(const int* __restrict__ src, const int* __restrict__ dst,
                              const int* __restrict__ et, int* __restrict__ run,
                              int* __restrict__ esrc, int E_){
  int e = blockIdx.x * 256 + threadIdx.x;
  if (e >= E_) return;
  int pos = atomicAdd(&run[dst[e] * NKEY8 + et[e]], 1);
  esrc[pos] = src[e];
}

__global__ void k_cvt(const float* __restrict__ in, __hip_bfloat16* __restrict__ out, int n){
  int i = blockIdx.x * 256 + threadIdx.x;
  if (i < n) out[i] = __float2bfloat16(in[i]);
}

// ---------------- weights: combine + pack into MFMA B-fragment order ----------------
__global__ void k_makeW(const float* __restrict__ basis, const float* __restrict__ comp,
                        const float* __restrict__ root, __hip_bfloat16* __restrict__ Wp){
  int idx = blockIdx.x * 256 + threadIdx.x;   // k*128 + n, k in [0,1152)
  int k = idx >> 7, n = idx & 127;
  float v;
  if (k < 1024){
    int r = k >> 7, i = k & 127;
    float s = 0.f;
    #pragma unroll
    for (int b = 0; b < 8; b++) s += comp[r * 8 + b] * basis[b * 16384 + i * 128 + n];
    v = s;
  } else {
    v = root[(k - 1024) * 128 + n];
  }
  int kt = k >> 5, kr = k & 31;
  int lane = (n & 15) | ((kr >> 3) << 4);
  int ii = kr & 7, nt = n >> 4;
  Wp[((size_t)(kt * 8 + nt) * 64 + lane) * 8 + ii] = __float2bfloat16(v);
}

__global__ void k_packG(const float* __restrict__ Wg, __hip_bfloat16* __restrict__ Wp){
  int idx = blockIdx.x * 256 + threadIdx.x;   // k*512 + n, k in [0,128)
  int k = idx >> 9, n = idx & 511;
  int kt = k >> 5, kr = k & 31;
  int lane = (n & 15) | ((kr >> 3) << 4);
  int ii = kr & 7, nt = n >> 4;
  Wp[((size_t)(kt * 32 + nt) * 64 + lane) * 8 + ii] = __float2bfloat16(Wg[idx]);
}

// ---------------- RGCN: CSR aggregation into bf16 [N, 1152] ----------------
__global__ void k_csr_agg(const int* __restrict__ ptr, const int* __restrict__ esrc,
                          const float* __restrict__ inv, const __hip_bfloat16* __restrict__ xb,
                          __hip_bfloat16* __restrict__ agg){
  int t = blockIdx.x, d = threadIdx.x;
  size_t ob = (size_t)t * 1152;
  #pragma unroll 1
  for (int r = 0; r < 8; r++){
    int beg = ptr[t * 8 + r], end = ptr[t * 8 + r + 1];
    float acc = 0.f;
    for (int e = beg; e < end; e++)
      acc += __bfloat162float(xb[(size_t)esrc[e] * DD + d]);
    agg[ob + r * 128 + d] = __float2bfloat16(acc * inv[t * 8 + r]);
  }
  agg[ob + 1024 + d] = xb[(size_t)t * DD + d];
}

// ---------------- MFMA GEMM with fused epilogues ----------------
// MODE 0: Cf = acc + bias (fp32 out)
// MODE 1: bf16 out = leaky(LN(acc + bias))           (RGCN layers 0/1)
// MODE 2: bf16 out = acc; also aS/aD dots, head = blockIdx.y   (GAT)
template<int MODE>
__launch_bounds__(256)
__global__ void k_gemm_mfma(const __hip_bfloat16* __restrict__ A, int lda, int M,
                            const __hip_bfloat16* __restrict__ Bp, int ntt,
                            const float* __restrict__ bias,
                            const float* __restrict__ ln_g, const float* __restrict__ ln_b,
                            const float* __restrict__ a_src, const float* __restrict__ a_dst,
                            float* __restrict__ Cf, __hip_bfloat16* __restrict__ Cb,
                            int ldc, int K, float* __restrict__ aS, float* __restrict__ aD){
  int wave = threadIdx.x >> 6, lane = threadIdx.x & 63;
  int nt0 = blockIdx.y << 3;
  int mbase = blockIdx.x * 128 + wave * 32;
  int r0 = min(mbase + (lane & 15), M - 1);
  int r1 = min(mbase + 16 + (lane & 15), M - 1);
  const __hip_bfloat16* a0p = A + (size_t)r0 * lda + ((lane >> 4) << 3);
  const __hip_bfloat16* a1p = A + (size_t)r1 * lda + ((lane >> 4) << 3);
  f32x4 acc[2][8];
  #pragma unroll
  for (int i = 0; i < 2; i++)
    #pragma unroll
    for (int j = 0; j < 8; j++) acc[i][j] = (f32x4){0.f, 0.f, 0.f, 0.f};

  for (int k0 = 0; k0 < K; k0 += 32){
    bf16x8 a0 = *(const bf16x8*)a0p; a0p += 32;
    bf16x8 a1 = *(const bf16x8*)a1p; a1p += 32;
    const bf16x8* bfr = (const bf16x8*)(Bp + (((size_t)(k0 >> 5) * ntt + nt0) * 64 + lane) * 8);
    #pragma unroll
    for (int nt = 0; nt < 8; nt++){
      bf16x8 b = bfr[(size_t)nt * 64];
      acc[0][nt] = __builtin_amdgcn_mfma_f32_16x16x32_bf16(a0, b, acc[0][nt], 0, 0, 0);
      acc[1][nt] = __builtin_amdgcn_mfma_f32_16x16x32_bf16(a1, b, acc[1][nt], 0, 0, 0);
    }
  }

  const int colb = lane & 15;
  const int lq = lane >> 4;

  float bias8[8], g8[8], b8[8], as8[8], ad8[8];
  #pragma unroll
  for (int nt = 0; nt < 8; nt++){
    int c = (nt << 4) + colb;                 // column within 128-wide group
    if (MODE == 0 || MODE == 1) bias8[nt] = bias ? bias[c] : 0.f;
    if (MODE == 1){ g8[nt] = ln_g[c]; b8[nt] = ln_b[c]; }
    if (MODE == 2){
      as8[nt] = a_src[blockIdx.y * 128 + c];
      ad8[nt] = a_dst[blockIdx.y * 128 + c];
    }
  }

  #pragma unroll
  for (int mt = 0; mt < 2; mt++){
    #pragma unroll
    for (int j = 0; j < 4; j++){
      int row = mbase + mt * 16 + lq * 4 + j;
      if (MODE == 0){
        if (row < M){
          #pragma unroll
          for (int nt = 0; nt < 8; nt++)
            Cf[(size_t)row * ldc + (nt << 4) + colb] = acc[mt][nt][j] + bias8[nt];
        }
      } else if (MODE == 1){
        float v[8]; float s = 0.f;
        #pragma unroll
        for (int nt = 0; nt < 8; nt++){ v[nt] = acc[mt][nt][j] + bias8[nt]; s += v[nt]; }
        #pragma unroll
        for (int o = 1; o < 16; o <<= 1) s += __shfl_xor(s, o);
        float mu = s * (1.f / 128.f);
        float q = 0.f;
        #pragma unroll
        for (int nt = 0; nt < 8; nt++){ float dd = v[nt] - mu; q += dd * dd; }
        #pragma unroll
        for (int o = 1; o < 16; o <<= 1) q += __shfl_xor(q, o);
        float rstd = rsqrtf(q * (1.f / 128.f) + 1e-5f);
        if (row < M){
          #pragma unroll
          for (int nt = 0; nt < 8; nt++){
            float y = leaky((v[nt] - mu) * rstd * g8[nt] + b8[nt], 0.1f);
            Cb[(size_t)row * ldc + (nt << 4) + colb] = __float2bfloat16(y);
          }
        }
      } else { // MODE 2
        float ds = 0.f, dd_ = 0.f;
        #pragma unroll
        for (int nt = 0; nt < 8; nt++){
          float t = acc[mt][nt][j];
          ds += t * as8[nt]; dd_ += t * ad8[nt];
          if (row < M)
            Cb[(size_t)row * ldc + blockIdx.y * 128 + (nt << 4) + colb] = __float2bfloat16(t);
        }
        #pragma unroll
        for (int o = 1; o < 16; o <<= 1){ ds += __shfl_xor(ds, o); dd_ += __shfl_xor(dd_, o); }
        if (colb == 0 && row < M){
          aS[(size_t)row * 4 + blockIdx.y] = ds;
          aD[(size_t)row * 4 + blockIdx.y] = dd_;
        }
      }
    }
  }
}

// ---------------- GAT: per-dst softmax coefficients (one THREAD per dst) ----------------
__global__ void k_gat_coef(const int* __restrict__ ptr, const int* __restrict__ esrc,
                           const float* __restrict__ aS, const float* __restrict__ aD,
                           float* __restrict__ cf, float* __restrict__ cfS,
                           float* __restrict__ den, int N_){
  int t = blockIdx.x * 256 + threadIdx.x;
  if (t >= N_) return;
  int beg = ptr[t * 8], end = ptr[t * 8 + 8];
  float4 ad = *(const float4*)(aD + (size_t)t * 4);
  float4 as = *(const float4*)(aS + (size_t)t * 4);
  float m0 = leaky(as.x + ad.x, 0.2f), m1 = leaky(as.y + ad.y, 0.2f);
  float m2 = leaky(as.z + ad.z, 0.2f), m3 = leaky(as.w + ad.w, 0.2f);
  for (int e = beg; e < end; e++){
    float4 a = *(const float4*)(aS + (size_t)esrc[e] * 4);
    m0 = fmaxf(m0, leaky(a.x + ad.x, 0.2f));
    m1 = fmaxf(m1, leaky(a.y + ad.y, 0.2f));
    m2 = fmaxf(m2, leaky(a.z + ad.z, 0.2f));
    m3 = fmaxf(m3, leaky(a.w + ad.w, 0.2f));
  }
  float s0 = __expf(leaky(as.x + ad.x, 0.2f) - m0);
  float s1 = __expf(leaky(as.y + ad.y, 0.2f) - m1);
  float s2 = __expf(leaky(as.z + ad.z, 0.2f) - m2);
  float s3 = __expf(leaky(as.w + ad.w, 0.2f) - m3);
  *(float4*)(cfS + (size_t)t * 4) = make_float4(s0, s1, s2, s3);
  float d0 = s0, d1 = s1, d2 = s2, d3 = s3;
  for (int e = beg; e < end; e++){
    float4 a = *(const float4*)(aS + (size_t)esrc[e] * 4);
    float x0 = __expf(leaky(a.x + ad.x, 0.2f) - m0);
    float x1 = __expf(leaky(a.y + ad.y, 0.2f) - m1);
    float x2 = __expf(leaky(a.z + ad.z, 0.2f) - m2);
    float x3 = __expf(leaky(a.w + ad.w, 0.2f) - m3);
    *(float4*)(cf + (size_t)e * 4) = make_float4(x0, x1, x2, x3);
    d0 += x0; d1 += x1; d2 += x2; d3 += x3;
  }
  *(float4*)(den + (size_t)t * 4) = make_float4(d0, d1, d2, d3);
}

// ---------------- GAT aggregation + head mean + bias + LN + leaky -> bf16 ----------------
__global__ void k_gat_agg(const int* __restrict__ ptr, const int* __restrict__ esrc,
                          const float* __restrict__ cf, const float* __restrict__ cfS,
                          const float* __restrict__ den, const __hip_bfloat16* __restrict__ hH,
                          const float* __restrict__ bias, const float* __restrict__ g,
                          const float* __restrict__ b, __hip_bfloat16* __restrict__ out){
  __shared__ float sm[4];
  int t = blockIdx.x, d = threadIdx.x;
  int beg = ptr[t * 8], end = ptr[t * 8 + 8];
  float4 cs = *(const float4*)(cfS + (size_t)t * 4);
  float4 dn = *(const float4*)(den + (size_t)t * 4);
  const __hip_bfloat16* hp = hH + (size_t)t * 512 + d;
  float ac0 = cs.x * __bfloat162float(hp[0]);
  float ac1 = cs.y * __bfloat162float(hp[128]);
  float ac2 = cs.z * __bfloat162float(hp[256]);
  float ac3 = cs.w * __bfloat162float(hp[384]);
  for (int e = beg; e < end; e++){
    float4 c = *(const float4*)(cf + (size_t)e * 4);
    const __hip_bfloat16* sp = hH + (size_t)esrc[e] * 512 + d;
    ac0 += c.x * __bfloat162float(sp[0]);
    ac1 += c.y * __bfloat162float(sp[128]);
    ac2 += c.z * __bfloat162float(sp[256]);
    ac3 += c.w * __bfloat162float(sp[384]);
  }
  float y = 0.25f * (ac0 / dn.x + ac1 / dn.y + ac2 / dn.z + ac3 / dn.w) + bias[d];
  // LayerNorm across 128 threads (2 waves)
  float s = y, q = y * y;
  for (int o = 1; o < 64; o <<= 1){ s += __shfl_xor(s, o); q += __shfl_xor(q, o); }
  int w = d >> 6;
  if ((d & 63) == 0){ sm[w * 2] = s; sm[w * 2 + 1] = q; }
  __syncthreads();
  float st = sm[0] + sm[2], qt = sm[1] + sm[3];
  float mu = st * (1.f / 128.f);
  float rstd = rsqrtf(qt * (1.f / 128.f) - mu * mu + 1e-5f);
  float yo = leaky((y - mu) * rstd * g[d] + b[d], 0.1f);
  out[(size_t)t * DD + d] = __float2bfloat16(yo);
}

__global__ void k_l2norm(float* __restrict__ X){
  int row  = blockIdx.x * 4 + (threadIdx.x >> 6);
  int lane = threadIdx.x & 63;
  float2 v = *(float2*)(X + (size_t)row * DD + lane * 2);
  float q = v.x * v.x + v.y * v.y;
  for (int o = 1; o < 64; o <<= 1) q += __shfl_xor(q, o);
  float sc = 1.0f / fmaxf(sqrtf(q), 1e-12f);
  v.x *= sc; v.y *= sc;
  *(float2*)(X + (size_t)row * DD + lane * 2) = v;
}

extern "C" void kernel_launch(void* const* d_in, const int* in_sizes, int n_in,
                              void* d_out, int out_size, void* d_ws, size_t ws_size,
                              hipStream_t stream){
  const float* x       = (const float*)d_in[0];
  const int*   ei      = (const int*)d_in[1];
  const int*   et      = (const int*)d_in[2];
  const float* r0_basis= (const float*)d_in[3];  const float* r0_comp = (const float*)d_in[4];
  const float* r0_root = (const float*)d_in[5];  const float* r0_bias = (const float*)d_in[6];
  const float* ln0_g   = (const float*)d_in[7];  const float* ln0_b   = (const float*)d_in[8];
  const float* r1_basis= (const float*)d_in[9];  const float* r1_comp = (const float*)d_in[10];
  const float* r1_root = (const float*)d_in[11]; const float* r1_bias = (const float*)d_in[12];
  const float* ln1_g   = (const float*)d_in[13]; const float* ln1_b   = (const float*)d_in[14];
  const float* gat_w   = (const float*)d_in[15]; const float* gat_asrc= (const float*)d_in[16];
  const float* gat_adst= (const float*)d_in[17]; const float* gat_bias= (const float*)d_in[18];
  const float* ln2_g   = (const float*)d_in[19]; const float* ln2_b   = (const float*)d_in[20];
  const float* r2_basis= (const float*)d_in[21]; const float* r2_comp = (const float*)d_in[22];
  const float* r2_root = (const float*)d_in[23]; const float* r2_bias = (const float*)d_in[24];

  const int N_ = in_sizes[0] / DD;
  const int E_ = in_sizes[2];
  const int NK = N_ * NKEY8;
  const int* src = ei;
  const int* dst = ei + E_;
  float* T2 = (float*)d_out;

  char* wp_ = (char*)d_ws;
  auto alloc = [&](size_t b)->void*{ void* p = wp_; wp_ += (b + 255) & ~(size_t)255; return p; };
  __hip_bfloat16* agg16 = (__hip_bfloat16*)alloc((size_t)N_ * 1152 * 2);  // also hosts hH16
  __hip_bfloat16* xb16  = (__hip_bfloat16*)alloc((size_t)N_ * DD * 2);
  float*          inv   = (float*)alloc((size_t)NK * 4);
  int*            ptrb  = (int*)alloc((size_t)(NK + 1) * 4);
  int*            cnt   = (int*)alloc((size_t)NK * 4);
  int*            run   = (int*)alloc((size_t)NK * 4);
  int*            esrc  = (int*)alloc((size_t)E_ * 4);
  int*            part  = (int*)alloc(512 * 4);
  float*          aS    = (float*)alloc((size_t)N_ * 4 * 4);
  float*          aD    = (float*)alloc((size_t)N_ * 4 * 4);
  float*          cf    = (float*)alloc((size_t)E_ * 4 * 4);
  float*          cfS   = (float*)alloc((size_t)N_ * 4 * 4);
  float*          den   = (float*)alloc((size_t)N_ * 4 * 4);
  __hip_bfloat16* Wp    = (__hip_bfloat16*)alloc((size_t)1152 * 128 * 2);
  __hip_bfloat16* WpG   = (__hip_bfloat16*)alloc((size_t)128 * 512 * 2);
  if ((size_t)(wp_ - (char*)d_ws) > ws_size) return;
  __hip_bfloat16* hH16 = agg16;

  const int Mb = (N_ + 127) / 128;
  const int nScanB = (NK + 1023) / 1024;

  // ---- CSR build (once; same graph for all layers) ----
  hipMemsetAsync(cnt, 0, (size_t)NK * 4, stream);
  k_hist<<<(E_ + 255) / 256, 256, 0, stream>>>(dst, et, cnt, E_);
  k_scan1<<<nScanB, 256, 0, stream>>>(cnt, ptrb, part, NK);
  k_scan2<<<1, 512, 0, stream>>>(part, nScanB);
  k_scan3<<<(NK + 1 + 255) / 256, 256, 0, stream>>>(ptrb, part, NK, E_);
  k_inv<<<(NK + 255) / 256, 256, 0, stream>>>(ptrb, inv, NK);
  hipMemcpyAsync(run, ptrb, (size_t)NK * 4, hipMemcpyDeviceToDevice, stream);
  k_scatter_pos<<<(E_ + 255) / 256, 256, 0, stream>>>(src, dst, et, run, esrc, E_);
  k_cvt<<<(N_ * DD + 255) / 256, 256, 0, stream>>>(x, xb16, N_ * DD);

  // ---- RGCN layer 0 (LN0+leaky fused) ----
  k_makeW<<<576, 256, 0, stream>>>(r0_basis, r0_comp, r0_root, Wp);
  k_csr_agg<<<N_, 128, 0, stream>>>(ptrb, esrc, inv, xb16, agg16);
  k_gemm_mfma<1><<<dim3(Mb, 1), 256, 0, stream>>>(agg16, 1152, N_, Wp, 8, r0_bias,
      ln0_g, ln0_b, nullptr, nullptr, nullptr, xb16, DD, 1152, nullptr, nullptr);

  // ---- RGCN layer 1 (LN1+leaky fused) ----
  k_makeW<<<576, 256, 0, stream>>>(r1_basis, r1_comp, r1_root, Wp);
  k_csr_agg<<<N_, 128, 0, stream>>>(ptrb, esrc, inv, xb16, agg16);
  k_gemm_mfma<1><<<dim3(Mb, 1), 256, 0, stream>>>(agg16, 1152, N_, Wp, 8, r1_bias,
      ln1_g, ln1_b, nullptr, nullptr, nullptr, xb16, DD, 1152, nullptr, nullptr);

  // ---- GAT (alpha fused in GEMM epilogue; softmax split; LN2+leaky fused in agg) ----
  k_packG<<<256, 256, 0, stream>>>(gat_w, WpG);
  k_gemm_mfma<2><<<dim3(Mb, 4), 256, 0, stream>>>(xb16, DD, N_, WpG, 32, nullptr,
      nullptr, nullptr, gat_asrc, gat_adst, nullptr, hH16, 512, DD, aS, aD);
  k_gat_coef<<<(N_ + 255) / 256, 256, 0, stream>>>(ptrb, esrc, aS, aD, cf, cfS, den, N_);
  k_gat_agg<<<N_, 128, 0, stream>>>(ptrb, esrc, cf, cfS, den, hH16, gat_bias,
                                    ln2_g, ln2_b, xb16);

  // ---- RGCN layer 2 -> d_out (fp32) + L2 normalize ----
  k_makeW<<<576, 256, 0, stream>>>(r2_basis, r2_comp, r2_root, Wp);
  k_csr_agg<<<N_, 128, 0, stream>>>(ptrb, esrc, inv, xb16, agg16);
  k_gemm_mfma<0><<<dim3(Mb, 1), 256, 0, stream>>>(agg16, 1152, N_, Wp, 8, r2_bias,
      nullptr, nullptr, nullptr, nullptr, T2, nullptr, DD, 1152, nullptr, nullptr);
  k_l2norm<<<N_ / 4, 256, 0, stream>>>(T2);
}

// Round 5
// 603.145 us; speedup vs baseline: 65.8994x; 1.0405x over previous
//
#include <hip/hip_runtime.h>
#include <hip/hip_bf16.h>

#define DD 128
#define NKEY8 8      // keys per dst = R
#define LDA_AGG 1056 // 1024 + 32 pad (non-pow2 row stride)

using bf16x8 = __attribute__((ext_vector_type(8))) __bf16;
using f32x4  = __attribute__((ext_vector_type(4))) float;

__device__ __forceinline__ float leaky(float x, float s){ return x > 0.f ? x : s * x; }
__device__ __forceinline__ float bflo(unsigned u){ return __uint_as_float(u << 16); }
__device__ __forceinline__ float bfhi(unsigned u){ return __uint_as_float(u & 0xffff0000u); }
__device__ __forceinline__ unsigned bfpack(float x, float y){
  __hip_bfloat16 hx = __float2bfloat16(x), hy = __float2bfloat16(y);
  unsigned short ux = *reinterpret_cast<unsigned short*>(&hx);
  unsigned short uy = *reinterpret_cast<unsigned short*>(&hy);
  return (unsigned)ux | ((unsigned)uy << 16);
}

// ---------------- CSR build (counting sort by key = dst*8 + etype) ----------------
__global__ void k_hist(const int* __restrict__ dst, const int* __restrict__ et,
                       int* __restrict__ cnt, int E_){
  int e = blockIdx.x * 256 + threadIdx.x;
  if (e < E_) atomicAdd(&cnt[dst[e] * NKEY8 + et[e]], 1);
}

__global__ void k_scan1(const int* __restrict__ cnt, int* __restrict__ ptr,
                        int* __restrict__ part, int n){
  __shared__ int sm[256];
  int tid = threadIdx.x;
  int base = blockIdx.x * 1024 + tid * 4;
  int a0 = base + 0 < n ? cnt[base + 0] : 0;
  int a1 = base + 1 < n ? cnt[base + 1] : 0;
  int a2 = base + 2 < n ? cnt[base + 2] : 0;
  int a3 = base + 3 < n ? cnt[base + 3] : 0;
  int s = a0 + a1 + a2 + a3;
  sm[tid] = s; __syncthreads();
  for (int off = 1; off < 256; off <<= 1){
    int v = tid >= off ? sm[tid - off] : 0;
    __syncthreads(); sm[tid] += v; __syncthreads();
  }
  int ex = sm[tid] - s;
  if (tid == 255) part[blockIdx.x] = sm[255];
  if (base + 0 < n) ptr[base + 0] = ex;
  if (base + 1 < n) ptr[base + 1] = ex + a0;
  if (base + 2 < n) ptr[base + 2] = ex + a0 + a1;
  if (base + 3 < n) ptr[base + 3] = ex + a0 + a1 + a2;
}

__global__ void k_scan2(int* __restrict__ part, int nb){  // single block, 512 thr
  __shared__ int sm[512];
  int tid = threadIdx.x;
  int v = tid < nb ? part[tid] : 0;
  sm[tid] = v; __syncthreads();
  for (int off = 1; off < 512; off <<= 1){
    int u = tid >= off ? sm[tid - off] : 0;
    __syncthreads(); sm[tid] += u; __syncthreads();
  }
  if (tid < nb) part[tid] = sm[tid] - v;  // exclusive
}

__global__ void k_scan3(int* __restrict__ ptr, const int* __restrict__ part, int n, int E_){
  int i = blockIdx.x * 256 + threadIdx.x;
  if (i < n) ptr[i] += part[i >> 10];
  if (i == n) ptr[n] = E_;
}

__global__ void k_inv(const int* __restrict__ ptr, float* __restrict__ inv, int n){
  int i = blockIdx.x * 256 + threadIdx.x;
  if (i < n) inv[i] = 1.0f / fmaxf((float)(ptr[i + 1] - ptr[i]), 1.0f);
}

__global__ void k_scatter_pos(const int* __restrict__ src, const int* __restrict__ dst,
                              const int* __restrict__ et, int* __restrict__ run,
                              int* __restrict__ esrc, int E_){
  int e = blockIdx.x * 256 + threadIdx.x;
  if (e >= E_) return;
  int pos = atomicAdd(&run[dst[e] * NKEY8 + et[e]], 1);
  esrc[pos] = src[e];
}

__global__ void k_cvt(const float* __restrict__ in, __hip_bfloat16* __restrict__ out, int n){
  int i = blockIdx.x * 256 + threadIdx.x;
  if (i < n) out[i] = __float2bfloat16(in[i]);
}

// ---------------- weights: combine + pack into MFMA B-fragment order ----------------
__global__ void k_makeW(const float* __restrict__ basis, const float* __restrict__ comp,
                        const float* __restrict__ root, __hip_bfloat16* __restrict__ Wp){
  int idx = blockIdx.x * 256 + threadIdx.x;   // k*128 + n, k in [0,1152)
  int k = idx >> 7, n = idx & 127;
  float v;
  if (k < 1024){
    int r = k >> 7, i = k & 127;
    float s = 0.f;
    #pragma unroll
    for (int b = 0; b < 8; b++) s += comp[r * 8 + b] * basis[b * 16384 + i * 128 + n];
    v = s;
  } else {
    v = root[(k - 1024) * 128 + n];
  }
  int kt = k >> 5, kr = k & 31;
  int lane = (n & 15) | ((kr >> 3) << 4);
  int ii = kr & 7, nt = n >> 4;
  Wp[((size_t)(kt * 8 + nt) * 64 + lane) * 8 + ii] = __float2bfloat16(v);
}

__global__ void k_packG(const float* __restrict__ Wg, __hip_bfloat16* __restrict__ Wp){
  int idx = blockIdx.x * 256 + threadIdx.x;   // k*512 + n, k in [0,128)
  int k = idx >> 9, n = idx & 511;
  int kt = k >> 5, kr = k & 31;
  int lane = (n & 15) | ((kr >> 3) << 4);
  int ii = kr & 7, nt = n >> 4;
  Wp[((size_t)(kt * 32 + nt) * 64 + lane) * 8 + ii] = __float2bfloat16(Wg[idx]);
}

// ---------------- RGCN: CSR aggregation into bf16 [N, 1024(+pad)] ----------------
// One wave per dst; lane = (edge-parity ep, d-group dg of 4 feats); 8B loads, 2 edges in flight.
__global__ void k_csr_agg(const int* __restrict__ ptr, const int* __restrict__ esrc,
                          const float* __restrict__ inv, const __hip_bfloat16* __restrict__ xb,
                          __hip_bfloat16* __restrict__ agg, int N_){
  int w = threadIdx.x >> 6, lane = threadIdx.x & 63;
  int t = blockIdx.x * 4 + w;
  if (t >= N_) return;
  int dg = lane & 31, ep = lane >> 5;
  const __hip_bfloat16* xbase = xb + dg * 4;
  size_t ob = (size_t)t * LDA_AGG;
  #pragma unroll 1
  for (int r = 0; r < 8; r++){
    int beg = ptr[t * 8 + r], end = ptr[t * 8 + r + 1];
    float a0 = 0.f, a1 = 0.f, a2 = 0.f, a3 = 0.f;
    for (int e = beg + ep; e < end; e += 2){
      int s = esrc[e];
      uint2 v = *(const uint2*)(xbase + (size_t)s * DD);
      a0 += bflo(v.x); a1 += bfhi(v.x);
      a2 += bflo(v.y); a3 += bfhi(v.y);
    }
    a0 += __shfl_xor(a0, 32); a1 += __shfl_xor(a1, 32);
    a2 += __shfl_xor(a2, 32); a3 += __shfl_xor(a3, 32);
    if (ep == 0){
      float iv = inv[t * 8 + r];
      uint2 o; o.x = bfpack(a0 * iv, a1 * iv); o.y = bfpack(a2 * iv, a3 * iv);
      *(uint2*)(agg + ob + r * 128 + dg * 4) = o;
    }
  }
}

// ---------------- MFMA GEMM, split-A (A1[K1] then A2[K2], lda2=128), fused epilogues ----------
// MODE 0: Cf = acc + bias (fp32). MODE 1: Cb = leaky(LN(acc+bias)). MODE 2: Cb = acc + aS/aD dots.
template<int MODE>
__launch_bounds__(256)
__global__ void k_gemm_mfma(const __hip_bfloat16* __restrict__ A1, int lda1, int K1,
                            const __hip_bfloat16* __restrict__ A2, int K2,
                            int M, const __hip_bfloat16* __restrict__ Bp, int ntt,
                            const float* __restrict__ bias,
                            const float* __restrict__ ln_g, const float* __restrict__ ln_b,
                            const float* __restrict__ a_src, const float* __restrict__ a_dst,
                            float* __restrict__ Cf, __hip_bfloat16* __restrict__ Cb,
                            int ldc, float* __restrict__ aS, float* __restrict__ aD){
  int wave = threadIdx.x >> 6, lane = threadIdx.x & 63;
  int nt0 = blockIdx.y << 3;
  int mbase = blockIdx.x * 128 + wave * 32;
  int r0 = min(mbase + (lane & 15), M - 1);
  int r1 = min(mbase + 16 + (lane & 15), M - 1);
  int koff = (lane >> 4) << 3;
  f32x4 acc[2][8];
  #pragma unroll
  for (int i = 0; i < 2; i++)
    #pragma unroll
    for (int j = 0; j < 8; j++) acc[i][j] = (f32x4){0.f, 0.f, 0.f, 0.f};

  int ktile = 0;
  {
    const __hip_bfloat16* a0p = A1 + (size_t)r0 * lda1 + koff;
    const __hip_bfloat16* a1p = A1 + (size_t)r1 * lda1 + koff;
    for (int k0 = 0; k0 < K1; k0 += 32, ++ktile){
      bf16x8 a0 = *(const bf16x8*)(a0p + k0);
      bf16x8 a1 = *(const bf16x8*)(a1p + k0);
      const bf16x8* bfr = (const bf16x8*)(Bp + (((size_t)ktile * ntt + nt0) * 64 + lane) * 8);
      #pragma unroll
      for (int nt = 0; nt < 8; nt++){
        bf16x8 b = bfr[(size_t)nt * 64];
        acc[0][nt] = __builtin_amdgcn_mfma_f32_16x16x32_bf16(a0, b, acc[0][nt], 0, 0, 0);
        acc[1][nt] = __builtin_amdgcn_mfma_f32_16x16x32_bf16(a1, b, acc[1][nt], 0, 0, 0);
      }
    }
  }
  if (A2){
    const __hip_bfloat16* a0p = A2 + (size_t)r0 * DD + koff;
    const __hip_bfloat16* a1p = A2 + (size_t)r1 * DD + koff;
    for (int k0 = 0; k0 < K2; k0 += 32, ++ktile){
      bf16x8 a0 = *(const bf16x8*)(a0p + k0);
      bf16x8 a1 = *(const bf16x8*)(a1p + k0);
      const bf16x8* bfr = (const bf16x8*)(Bp + (((size_t)ktile * ntt + nt0) * 64 + lane) * 8);
      #pragma unroll
      for (int nt = 0; nt < 8; nt++){
        bf16x8 b = bfr[(size_t)nt * 64];
        acc[0][nt] = __builtin_amdgcn_mfma_f32_16x16x32_bf16(a0, b, acc[0][nt], 0, 0, 0);
        acc[1][nt] = __builtin_amdgcn_mfma_f32_16x16x32_bf16(a1, b, acc[1][nt], 0, 0, 0);
      }
    }
  }

  const int colb = lane & 15;
  const int lq = lane >> 4;

  float bias8[8], g8[8], b8[8], as8[8], ad8[8];
  #pragma unroll
  for (int nt = 0; nt < 8; nt++){
    int c = (nt << 4) + colb;
    if (MODE == 0 || MODE == 1) bias8[nt] = bias ? bias[c] : 0.f;
    if (MODE == 1){ g8[nt] = ln_g[c]; b8[nt] = ln_b[c]; }
    if (MODE == 2){
      as8[nt] = a_src[blockIdx.y * 128 + c];
      ad8[nt] = a_dst[blockIdx.y * 128 + c];
    }
  }

  #pragma unroll
  for (int mt = 0; mt < 2; mt++){
    #pragma unroll
    for (int j = 0; j < 4; j++){
      int row = mbase + mt * 16 + lq * 4 + j;
      if (MODE == 0){
        if (row < M){
          #pragma unroll
          for (int nt = 0; nt < 8; nt++)
            Cf[(size_t)row * ldc + (nt << 4) + colb] = acc[mt][nt][j] + bias8[nt];
        }
      } else if (MODE == 1){
        float v[8]; float s = 0.f;
        #pragma unroll
        for (int nt = 0; nt < 8; nt++){ v[nt] = acc[mt][nt][j] + bias8[nt]; s += v[nt]; }
        #pragma unroll
        for (int o = 1; o < 16; o <<= 1) s += __shfl_xor(s, o);
        float mu = s * (1.f / 128.f);
        float q = 0.f;
        #pragma unroll
        for (int nt = 0; nt < 8; nt++){ float dd = v[nt] - mu; q += dd * dd; }
        #pragma unroll
        for (int o = 1; o < 16; o <<= 1) q += __shfl_xor(q, o);
        float rstd = rsqrtf(q * (1.f / 128.f) + 1e-5f);
        if (row < M){
          #pragma unroll
          for (int nt = 0; nt < 8; nt++){
            float y = leaky((v[nt] - mu) * rstd * g8[nt] + b8[nt], 0.1f);
            Cb[(size_t)row * ldc + (nt << 4) + colb] = __float2bfloat16(y);
          }
        }
      } else { // MODE 2
        float ds = 0.f, dd_ = 0.f;
        #pragma unroll
        for (int nt = 0; nt < 8; nt++){
          float t = acc[mt][nt][j];
          ds += t * as8[nt]; dd_ += t * ad8[nt];
          if (row < M)
            Cb[(size_t)row * ldc + blockIdx.y * 128 + (nt << 4) + colb] = __float2bfloat16(t);
        }
        #pragma unroll
        for (int o = 1; o < 16; o <<= 1){ ds += __shfl_xor(ds, o); dd_ += __shfl_xor(dd_, o); }
        if (colb == 0 && row < M){
          aS[(size_t)row * 4 + blockIdx.y] = ds;
          aD[(size_t)row * 4 + blockIdx.y] = dd_;
        }
      }
    }
  }
}

// ---------------- GAT: per-dst softmax coefficients (one THREAD per dst) ----------------
__global__ void k_gat_coef(const int* __restrict__ ptr, const int* __restrict__ esrc,
                           const float* __restrict__ aS, const float* __restrict__ aD,
                           float* __restrict__ cf, float* __restrict__ cfS,
                           float* __restrict__ den, int N_){
  int t = blockIdx.x * 256 + threadIdx.x;
  if (t >= N_) return;
  int beg = ptr[t * 8], end = ptr[t * 8 + 8];
  float4 ad = *(const float4*)(aD + (size_t)t * 4);
  float4 as = *(const float4*)(aS + (size_t)t * 4);
  float m0 = leaky(as.x + ad.x, 0.2f), m1 = leaky(as.y + ad.y, 0.2f);
  float m2 = leaky(as.z + ad.z, 0.2f), m3 = leaky(as.w + ad.w, 0.2f);
  for (int e = beg; e < end; e++){
    float4 a = *(const float4*)(aS + (size_t)esrc[e] * 4);
    m0 = fmaxf(m0, leaky(a.x + ad.x, 0.2f));
    m1 = fmaxf(m1, leaky(a.y + ad.y, 0.2f));
    m2 = fmaxf(m2, leaky(a.z + ad.z, 0.2f));
    m3 = fmaxf(m3, leaky(a.w + ad.w, 0.2f));
  }
  float s0 = __expf(leaky(as.x + ad.x, 0.2f) - m0);
  float s1 = __expf(leaky(as.y + ad.y, 0.2f) - m1);
  float s2 = __expf(leaky(as.z + ad.z, 0.2f) - m2);
  float s3 = __expf(leaky(as.w + ad.w, 0.2f) - m3);
  *(float4*)(cfS + (size_t)t * 4) = make_float4(s0, s1, s2, s3);
  float d0 = s0, d1 = s1, d2 = s2, d3 = s3;
  for (int e = beg; e < end; e++){
    float4 a = *(const float4*)(aS + (size_t)esrc[e] * 4);
    float x0 = __expf(leaky(a.x + ad.x, 0.2f) - m0);
    float x1 = __expf(leaky(a.y + ad.y, 0.2f) - m1);
    float x2 = __expf(leaky(a.z + ad.z, 0.2f) - m2);
    float x3 = __expf(leaky(a.w + ad.w, 0.2f) - m3);
    *(float4*)(cf + (size_t)e * 4) = make_float4(x0, x1, x2, x3);
    d0 += x0; d1 += x1; d2 += x2; d3 += x3;
  }
  *(float4*)(den + (size_t)t * 4) = make_float4(d0, d1, d2, d3);
}

// ---------------- GAT aggregation: thread=(head,d-group), 8B loads, LDS head-mean + LN ----------
__global__ void k_gat_agg(const int* __restrict__ ptr, const int* __restrict__ esrc,
                          const float* __restrict__ cf, const float* __restrict__ cfS,
                          const float* __restrict__ den, const __hip_bfloat16* __restrict__ hH,
                          const float* __restrict__ bias, const float* __restrict__ g,
                          const float* __restrict__ b, __hip_bfloat16* __restrict__ out){
  __shared__ float sm[4][128];
  __shared__ float red[4];
  int t = blockIdx.x, tid = threadIdx.x;
  int h = tid >> 5, dg = tid & 31;
  int beg = ptr[t * 8], end = ptr[t * 8 + 8];
  const __hip_bfloat16* base = hH + (size_t)h * 128 + dg * 4;
  uint2 v = *(const uint2*)(base + (size_t)t * 512);
  float cs = cfS[(size_t)t * 4 + h];
  float a0 = cs * bflo(v.x), a1 = cs * bfhi(v.x);
  float a2 = cs * bflo(v.y), a3 = cs * bfhi(v.y);
  int e = beg;
  for (; e + 1 < end; e += 2){
    int s0 = esrc[e], s1 = esrc[e + 1];
    float c0 = cf[(size_t)e * 4 + h], c1 = cf[(size_t)(e + 1) * 4 + h];
    uint2 u0 = *(const uint2*)(base + (size_t)s0 * 512);
    uint2 u1 = *(const uint2*)(base + (size_t)s1 * 512);
    a0 += c0 * bflo(u0.x) + c1 * bflo(u1.x);
    a1 += c0 * bfhi(u0.x) + c1 * bfhi(u1.x);
    a2 += c0 * bflo(u0.y) + c1 * bflo(u1.y);
    a3 += c0 * bfhi(u0.y) + c1 * bfhi(u1.y);
  }
  if (e < end){
    int s0 = esrc[e]; float c0 = cf[(size_t)e * 4 + h];
    uint2 u0 = *(const uint2*)(base + (size_t)s0 * 512);
    a0 += c0 * bflo(u0.x); a1 += c0 * bfhi(u0.x);
    a2 += c0 * bflo(u0.y); a3 += c0 * bfhi(u0.y);
  }
  float dinv = 0.25f / den[(size_t)t * 4 + h];
  sm[h][dg * 4 + 0] = a0 * dinv; sm[h][dg * 4 + 1] = a1 * dinv;
  sm[h][dg * 4 + 2] = a2 * dinv; sm[h][dg * 4 + 3] = a3 * dinv;
  __syncthreads();
  int d = tid;
  float y = sm[0][d] + sm[1][d] + sm[2][d] + sm[3][d] + bias[d];
  float s = y, q = y * y;
  for (int o = 1; o < 64; o <<= 1){ s += __shfl_xor(s, o); q += __shfl_xor(q, o); }
  int w = d >> 6;
  if ((d & 63) == 0){ red[w * 2] = s; red[w * 2 + 1] = q; }
  __syncthreads();
  float st = red[0] + red[2], qt = red[1] + red[3];
  float mu = st * (1.f / 128.f);
  float rstd = rsqrtf(qt * (1.f / 128.f) - mu * mu + 1e-5f);
  float yo = leaky((y - mu) * rstd * g[d] + b[d], 0.1f);
  out[(size_t)t * DD + d] = __float2bfloat16(yo);
}

__global__ void k_l2norm(float* __restrict__ X){
  int row  = blockIdx.x * 4 + (threadIdx.x >> 6);
  int lane = threadIdx.x & 63;
  float2 v = *(float2*)(X + (size_t)row * DD + lane * 2);
  float q = v.x * v.x + v.y * v.y;
  for (int o = 1; o < 64; o <<= 1) q += __shfl_xor(q, o);
  float sc = 1.0f / fmaxf(sqrtf(q), 1e-12f);
  v.x *= sc; v.y *= sc;
  *(float2*)(X + (size_t)row * DD + lane * 2) = v;
}

extern "C" void kernel_launch(void* const* d_in, const int* in_sizes, int n_in,
                              void* d_out, int out_size, void* d_ws, size_t ws_size,
                              hipStream_t stream){
  const float* x       = (const float*)d_in[0];
  const int*   ei      = (const int*)d_in[1];
  const int*   et      = (const int*)d_in[2];
  const float* r0_basis= (const float*)d_in[3];  const float* r0_comp = (const float*)d_in[4];
  const float* r0_root = (const float*)d_in[5];  const float* r0_bias = (const float*)d_in[6];
  const float* ln0_g   = (const float*)d_in[7];  const float* ln0_b   = (const float*)d_in[8];
  const float* r1_basis= (const float*)d_in[9];  const float* r1_comp = (const float*)d_in[10];
  const float* r1_root = (const float*)d_in[11]; const float* r1_bias = (const float*)d_in[12];
  const float* ln1_g   = (const float*)d_in[13]; const float* ln1_b   = (const float*)d_in[14];
  const float* gat_w   = (const float*)d_in[15]; const float* gat_asrc= (const float*)d_in[16];
  const float* gat_adst= (const float*)d_in[17]; const float* gat_bias= (const float*)d_in[18];
  const float* ln2_g   = (const float*)d_in[19]; const float* ln2_b   = (const float*)d_in[20];
  const float* r2_basis= (const float*)d_in[21]; const float* r2_comp = (const float*)d_in[22];
  const float* r2_root = (const float*)d_in[23]; const float* r2_bias = (const float*)d_in[24];

  const int N_ = in_sizes[0] / DD;
  const int E_ = in_sizes[2];
  const int NK = N_ * NKEY8;
  const int* src = ei;
  const int* dst = ei + E_;
  float* T2 = (float*)d_out;

  char* wp_ = (char*)d_ws;
  auto alloc = [&](size_t b)->void*{ void* p = wp_; wp_ += (b + 255) & ~(size_t)255; return p; };
  __hip_bfloat16* agg16 = (__hip_bfloat16*)alloc((size_t)N_ * LDA_AGG * 2);  // also hosts hH16
  __hip_bfloat16* xb16  = (__hip_bfloat16*)alloc((size_t)N_ * DD * 2);
  float*          inv   = (float*)alloc((size_t)NK * 4);
  int*            ptrb  = (int*)alloc((size_t)(NK + 1) * 4);
  int*            cnt   = (int*)alloc((size_t)NK * 4);
  int*            run   = (int*)alloc((size_t)NK * 4);
  int*            esrc  = (int*)alloc((size_t)E_ * 4);
  int*            part  = (int*)alloc(512 * 4);
  float*          aS    = (float*)alloc((size_t)N_ * 4 * 4);
  float*          aD    = (float*)alloc((size_t)N_ * 4 * 4);
  float*          cf    = (float*)alloc((size_t)E_ * 4 * 4);
  float*          cfS   = (float*)alloc((size_t)N_ * 4 * 4);
  float*          den   = (float*)alloc((size_t)N_ * 4 * 4);
  __hip_bfloat16* Wp    = (__hip_bfloat16*)alloc((size_t)1152 * 128 * 2);
  __hip_bfloat16* WpG   = (__hip_bfloat16*)alloc((size_t)128 * 512 * 2);
  if ((size_t)(wp_ - (char*)d_ws) > ws_size) return;
  __hip_bfloat16* hH16 = agg16;

  const int Mb = (N_ + 127) / 128;
  const int nScanB = (NK + 1023) / 1024;

  // ---- CSR build (same graph for all layers) ----
  hipMemsetAsync(cnt, 0, (size_t)NK * 4, stream);
  k_hist<<<(E_ + 255) / 256, 256, 0, stream>>>(dst, et, cnt, E_);
  k_scan1<<<nScanB, 256, 0, stream>>>(cnt, ptrb, part, NK);
  k_scan2<<<1, 512, 0, stream>>>(part, nScanB);
  k_scan3<<<(NK + 1 + 255) / 256, 256, 0, stream>>>(ptrb, part, NK, E_);
  k_inv<<<(NK + 255) / 256, 256, 0, stream>>>(ptrb, inv, NK);
  hipMemcpyAsync(run, ptrb, (size_t)NK * 4, hipMemcpyDeviceToDevice, stream);
  k_scatter_pos<<<(E_ + 255) / 256, 256, 0, stream>>>(src, dst, et, run, esrc, E_);
  k_cvt<<<(N_ * DD + 255) / 256, 256, 0, stream>>>(x, xb16, N_ * DD);

  // ---- RGCN layer 0 (LN0+leaky fused) ----
  k_makeW<<<576, 256, 0, stream>>>(r0_basis, r0_comp, r0_root, Wp);
  k_csr_agg<<<(N_ + 3) / 4, 256, 0, stream>>>(ptrb, esrc, inv, xb16, agg16, N_);
  k_gemm_mfma<1><<<dim3(Mb, 1), 256, 0, stream>>>(agg16, LDA_AGG, 1024, xb16, 128, N_, Wp, 8,
      r0_bias, ln0_g, ln0_b, nullptr, nullptr, nullptr, xb16, DD, nullptr, nullptr);

  // ---- RGCN layer 1 (LN1+leaky fused) ----
  k_makeW<<<576, 256, 0, stream>>>(r1_basis, r1_comp, r1_root, Wp);
  k_csr_agg<<<(N_ + 3) / 4, 256, 0, stream>>>(ptrb, esrc, inv, xb16, agg16, N_);
  k_gemm_mfma<1><<<dim3(Mb, 1), 256, 0, stream>>>(agg16, LDA_AGG, 1024, xb16, 128, N_, Wp, 8,
      r1_bias, ln1_g, ln1_b, nullptr, nullptr, nullptr, xb16, DD, nullptr, nullptr);

  // ---- GAT ----
  k_packG<<<256, 256, 0, stream>>>(gat_w, WpG);
  k_gemm_mfma<2><<<dim3(Mb, 4), 256, 0, stream>>>(xb16, DD, 128, nullptr, 0, N_, WpG, 32,
      nullptr, nullptr, nullptr, gat_asrc, gat_adst, nullptr, hH16, 512, aS, aD);
  k_gat_coef<<<(N_ + 255) / 256, 256, 0, stream>>>(ptrb, esrc, aS, aD, cf, cfS, den, N_);
  k_gat_agg<<<N_, 128, 0, stream>>>(ptrb, esrc, cf, cfS, den, hH16, gat_bias,
                                    ln2_g, ln2_b, xb16);

  // ---- RGCN layer 2 -> d_out (fp32) + L2 normalize ----
  k_makeW<<<576, 256, 0, stream>>>(r2_basis, r2_comp, r2_root, Wp);
  k_csr_agg<<<(N_ + 3) / 4, 256, 0, stream>>>(ptrb, esrc, inv, xb16, agg16, N_);
  k_gemm_mfma<0><<<dim3(Mb, 1), 256, 0, stream>>>(agg16, LDA_AGG, 1024, xb16, 128, N_, Wp, 8,
      r2_bias, nullptr, nullptr, nullptr, nullptr, T2, nullptr, DD, nullptr, nullptr);
  k_l2norm<<<N_ / 4, 256, 0, stream>>>(T2);
}

// Round 6
// 558.250 us; speedup vs baseline: 71.1991x; 1.0804x over previous
//
#include <hip/hip_runtime.h>
#include <hip/hip_bf16.h>

#define DD 128
#define NKEY8 8      // keys per dst = R
#define LDA_AGG 1056 // 1024 + 32 pad (non-pow2 row stride)

using bf16x8 = __attribute__((ext_vector_type(8))) __bf16;
using f32x4  = __attribute__((ext_vector_type(4))) float;

__device__ __forceinline__ float leaky(float x, float s){ return x > 0.f ? x : s * x; }
__device__ __forceinline__ float bflo(unsigned u){ return __uint_as_float(u << 16); }
__device__ __forceinline__ float bfhi(unsigned u){ return __uint_as_float(u & 0xffff0000u); }
__device__ __forceinline__ unsigned bfpack(float x, float y){
  __hip_bfloat16 hx = __float2bfloat16(x), hy = __float2bfloat16(y);
  unsigned short ux = *reinterpret_cast<unsigned short*>(&hx);
  unsigned short uy = *reinterpret_cast<unsigned short*>(&hy);
  return (unsigned)ux | ((unsigned)uy << 16);
}

// ---------------- CSR build (counting sort by key = dst*8 + etype) ----------------
__global__ void k_hist(const int* __restrict__ dst, const int* __restrict__ et,
                       int* __restrict__ cnt, int E_){
  int e = blockIdx.x * 256 + threadIdx.x;
  if (e < E_) atomicAdd(&cnt[dst[e] * NKEY8 + et[e]], 1);
}

__global__ void k_scan1(const int* __restrict__ cnt, int* __restrict__ ptr,
                        int* __restrict__ part, int n){
  __shared__ int sm[256];
  int tid = threadIdx.x;
  int base = blockIdx.x * 1024 + tid * 4;
  int a0 = base + 0 < n ? cnt[base + 0] : 0;
  int a1 = base + 1 < n ? cnt[base + 1] : 0;
  int a2 = base + 2 < n ? cnt[base + 2] : 0;
  int a3 = base + 3 < n ? cnt[base + 3] : 0;
  int s = a0 + a1 + a2 + a3;
  sm[tid] = s; __syncthreads();
  for (int off = 1; off < 256; off <<= 1){
    int v = tid >= off ? sm[tid - off] : 0;
    __syncthreads(); sm[tid] += v; __syncthreads();
  }
  int ex = sm[tid] - s;
  if (tid == 255) part[blockIdx.x] = sm[255];
  if (base + 0 < n) ptr[base + 0] = ex;
  if (base + 1 < n) ptr[base + 1] = ex + a0;
  if (base + 2 < n) ptr[base + 2] = ex + a0 + a1;
  if (base + 3 < n) ptr[base + 3] = ex + a0 + a1 + a2;
}

__global__ void k_scan2(int* __restrict__ part, int nb){  // single block, 512 thr
  __shared__ int sm[512];
  int tid = threadIdx.x;
  int v = tid < nb ? part[tid] : 0;
  sm[tid] = v; __syncthreads();
  for (int off = 1; off < 512; off <<= 1){
    int u = tid >= off ? sm[tid - off] : 0;
    __syncthreads(); sm[tid] += u; __syncthreads();
  }
  if (tid < nb) part[tid] = sm[tid] - v;  // exclusive
}

__global__ void k_scan3(int* __restrict__ ptr, const int* __restrict__ part, int n, int E_){
  int i = blockIdx.x * 256 + threadIdx.x;
  if (i < n) ptr[i] += part[i >> 10];
  if (i == n) ptr[n] = E_;
}

__global__ void k_inv(const int* __restrict__ ptr, float* __restrict__ inv, int n){
  int i = blockIdx.x * 256 + threadIdx.x;
  if (i < n) inv[i] = 1.0f / fmaxf((float)(ptr[i + 1] - ptr[i]), 1.0f);
}

__global__ void k_scatter_pos(const int* __restrict__ src, const int* __restrict__ dst,
                              const int* __restrict__ et, int* __restrict__ run,
                              int* __restrict__ esrc, int E_){
  int e = blockIdx.x * 256 + threadIdx.x;
  if (e >= E_) return;
  int pos = atomicAdd(&run[dst[e] * NKEY8 + et[e]], 1);
  esrc[pos] = src[e];
}

__global__ void k_cvt(const float* __restrict__ in, __hip_bfloat16* __restrict__ out, int n){
  int i = blockIdx.x * 256 + threadIdx.x;
  if (i < n) out[i] = __float2bfloat16(in[i]);
}

// ---------------- weights: combine + pack into MFMA B-fragment order ----------------
__global__ void k_makeW(const float* __restrict__ basis, const float* __restrict__ comp,
                        const float* __restrict__ root, __hip_bfloat16* __restrict__ Wp){
  int idx = blockIdx.x * 256 + threadIdx.x;   // k*128 + n, k in [0,1152)
  int k = idx >> 7, n = idx & 127;
  float v;
  if (k < 1024){
    int r = k >> 7, i = k & 127;
    float s = 0.f;
    #pragma unroll
    for (int b = 0; b < 8; b++) s += comp[r * 8 + b] * basis[b * 16384 + i * 128 + n];
    v = s;
  } else {
    v = root[(k - 1024) * 128 + n];
  }
  int kt = k >> 5, kr = k & 31;
  int lane = (n & 15) | ((kr >> 3) << 4);
  int ii = kr & 7, nt = n >> 4;
  Wp[((size_t)(kt * 8 + nt) * 64 + lane) * 8 + ii] = __float2bfloat16(v);
}

// Wstack[h*128+i][n] = Wg[i][h*128+n], packed (ntt=8)
__global__ void k_packGZ(const float* __restrict__ Wg, __hip_bfloat16* __restrict__ Wp){
  int idx = blockIdx.x * 256 + threadIdx.x;   // k*128 + n, k in [0,512)
  int k = idx >> 7, n = idx & 127;
  int h = k >> 7, i = k & 127;
  float v = Wg[(size_t)i * 512 + h * 128 + n];
  int kt = k >> 5, kr = k & 31;
  int lane = (n & 15) | ((kr >> 3) << 4);
  int ii = kr & 7, nt = n >> 4;
  Wp[((size_t)(kt * 8 + nt) * 64 + lane) * 8 + ii] = __float2bfloat16(v);
}

// vT[sd][h][i] = sum_o Wg[i, h*128+o] * a_{src/dst}[h,o]
__global__ void k_valpha(const float* __restrict__ Wg, const float* __restrict__ a_src,
                         const float* __restrict__ a_dst, float* __restrict__ vT){
  int id = blockIdx.x * 256 + threadIdx.x;   // [0,1024)
  int sd = id >> 9, h = (id >> 7) & 3, i = id & 127;
  const float* a = (sd ? a_dst : a_src) + h * 128;
  const float* w = Wg + (size_t)i * 512 + h * 128;
  float s = 0.f;
  #pragma unroll 4
  for (int o = 0; o < 128; o++) s += w[o] * a[o];
  vT[(size_t)sd * 512 + h * 128 + i] = s;
}

// aS/aD from x directly: wave per node, 16 lanes per head
__global__ void k_av(const __hip_bfloat16* __restrict__ xb, const float* __restrict__ vT,
                     float* __restrict__ aS, float* __restrict__ aD, int N_){
  int node = blockIdx.x * 4 + (threadIdx.x >> 6);
  if (node >= N_) return;
  int lane = threadIdx.x & 63;
  int h = lane >> 4, dg = lane & 15;
  uint4 u = *(const uint4*)(xb + (size_t)node * DD + dg * 8);
  const float* vs = vT + h * 128 + dg * 8;
  const float* vd = vT + 512 + h * 128 + dg * 8;
  float ss = 0.f, sd = 0.f;
  #pragma unroll
  for (int w = 0; w < 4; w++){
    unsigned uw = ((const unsigned*)&u)[w];
    float f0 = bflo(uw), f1 = bfhi(uw);
    ss += f0 * vs[w * 2] + f1 * vs[w * 2 + 1];
    sd += f0 * vd[w * 2] + f1 * vd[w * 2 + 1];
  }
  for (int o = 1; o < 16; o <<= 1){ ss += __shfl_xor(ss, o); sd += __shfl_xor(sd, o); }
  if (dg == 0){ aS[(size_t)node * 4 + h] = ss; aD[(size_t)node * 4 + h] = sd; }
}

// ---------------- RGCN: CSR aggregation into bf16 [N, 1024(+pad)] ----------------
__global__ void k_csr_agg(const int* __restrict__ ptr, const int* __restrict__ esrc,
                          const float* __restrict__ inv, const __hip_bfloat16* __restrict__ xb,
                          __hip_bfloat16* __restrict__ agg, int N_){
  int w = threadIdx.x >> 6, lane = threadIdx.x & 63;
  int t = blockIdx.x * 4 + w;
  if (t >= N_) return;
  int dg = lane & 31, ep = lane >> 5;
  const __hip_bfloat16* xbase = xb + dg * 4;
  size_t ob = (size_t)t * LDA_AGG;
  #pragma unroll 1
  for (int r = 0; r < 8; r++){
    int beg = ptr[t * 8 + r], end = ptr[t * 8 + r + 1];
    float a0 = 0.f, a1 = 0.f, a2 = 0.f, a3 = 0.f;
    for (int e = beg + ep; e < end; e += 2){
      int s = esrc[e];
      uint2 v = *(const uint2*)(xbase + (size_t)s * DD);
      a0 += bflo(v.x); a1 += bfhi(v.x);
      a2 += bflo(v.y); a3 += bfhi(v.y);
    }
    a0 += __shfl_xor(a0, 32); a1 += __shfl_xor(a1, 32);
    a2 += __shfl_xor(a2, 32); a3 += __shfl_xor(a3, 32);
    if (ep == 0){
      float iv = inv[t * 8 + r];
      uint2 o; o.x = bfpack(a0 * iv, a1 * iv); o.y = bfpack(a2 * iv, a3 * iv);
      *(uint2*)(agg + ob + r * 128 + dg * 4) = o;
    }
  }
}

// ---------------- GAT: coef-weighted aggregation of x into z[N,512] ----------------
__global__ void k_zagg(const int* __restrict__ ptr, const int* __restrict__ esrc,
                       const float* __restrict__ cf, const float* __restrict__ cfS,
                       const float* __restrict__ den, const __hip_bfloat16* __restrict__ xb,
                       __hip_bfloat16* __restrict__ z, int N_){
  int w = threadIdx.x >> 6, lane = threadIdx.x & 63;
  int t = blockIdx.x * 4 + w;
  if (t >= N_) return;
  int dg = lane & 31, ep = lane >> 5;
  int beg = ptr[t * 8], end = ptr[t * 8 + 8];
  float acc[4][4];
  #pragma unroll
  for (int h = 0; h < 4; h++)
    #pragma unroll
    for (int j = 0; j < 4; j++) acc[h][j] = 0.f;
  const __hip_bfloat16* xbase = xb + dg * 4;
  for (int e = beg + ep; e < end; e += 2){
    int s = esrc[e];
    uint2 v = *(const uint2*)(xbase + (size_t)s * DD);
    float4 c = *(const float4*)(cf + (size_t)e * 4);
    float f0 = bflo(v.x), f1 = bfhi(v.x), f2 = bflo(v.y), f3 = bfhi(v.y);
    const float* cp = (const float*)&c;
    #pragma unroll
    for (int h = 0; h < 4; h++){
      acc[h][0] += cp[h] * f0; acc[h][1] += cp[h] * f1;
      acc[h][2] += cp[h] * f2; acc[h][3] += cp[h] * f3;
    }
  }
  #pragma unroll
  for (int h = 0; h < 4; h++)
    #pragma unroll
    for (int j = 0; j < 4; j++) acc[h][j] += __shfl_xor(acc[h][j], 32);
  if (ep == 0){
    uint2 v = *(const uint2*)(xbase + (size_t)t * DD);
    float f0 = bflo(v.x), f1 = bfhi(v.x), f2 = bflo(v.y), f3 = bfhi(v.y);
    float4 cs = *(const float4*)(cfS + (size_t)t * 4);
    float4 dn = *(const float4*)(den + (size_t)t * 4);
    const float* csp = (const float*)&cs;
    const float* dnp = (const float*)&dn;
    #pragma unroll
    for (int h = 0; h < 4; h++){
      float sc = 0.25f / dnp[h];
      float y0 = (acc[h][0] + csp[h] * f0) * sc;
      float y1 = (acc[h][1] + csp[h] * f1) * sc;
      float y2 = (acc[h][2] + csp[h] * f2) * sc;
      float y3 = (acc[h][3] + csp[h] * f3) * sc;
      uint2 o; o.x = bfpack(y0, y1); o.y = bfpack(y2, y3);
      *(uint2*)(z + (size_t)t * 512 + h * 128 + dg * 4) = o;
    }
  }
}

// ---------------- MFMA GEMM, split-A, fused epilogues ----------------
// MODE 1: Cb = leaky(LN(acc+bias)).  MODE 3: Cf = L2normalize(acc+bias).
template<int MODE>
__launch_bounds__(256)
__global__ void k_gemm_mfma(const __hip_bfloat16* __restrict__ A1, int lda1, int K1,
                            const __hip_bfloat16* __restrict__ A2, int K2,
                            int M, const __hip_bfloat16* __restrict__ Bp, int ntt,
                            const float* __restrict__ bias,
                            const float* __restrict__ ln_g, const float* __restrict__ ln_b,
                            float* __restrict__ Cf, __hip_bfloat16* __restrict__ Cb,
                            int ldc){
  int wave = threadIdx.x >> 6, lane = threadIdx.x & 63;
  int nt0 = blockIdx.y << 3;
  int mbase = blockIdx.x * 128 + wave * 32;
  int r0 = min(mbase + (lane & 15), M - 1);
  int r1 = min(mbase + 16 + (lane & 15), M - 1);
  int koff = (lane >> 4) << 3;
  f32x4 acc[2][8];
  #pragma unroll
  for (int i = 0; i < 2; i++)
    #pragma unroll
    for (int j = 0; j < 8; j++) acc[i][j] = (f32x4){0.f, 0.f, 0.f, 0.f};

  int ktile = 0;
  {
    const __hip_bfloat16* a0p = A1 + (size_t)r0 * lda1 + koff;
    const __hip_bfloat16* a1p = A1 + (size_t)r1 * lda1 + koff;
    for (int k0 = 0; k0 < K1; k0 += 32, ++ktile){
      bf16x8 a0 = *(const bf16x8*)(a0p + k0);
      bf16x8 a1 = *(const bf16x8*)(a1p + k0);
      const bf16x8* bfr = (const bf16x8*)(Bp + (((size_t)ktile * ntt + nt0) * 64 + lane) * 8);
      #pragma unroll
      for (int nt = 0; nt < 8; nt++){
        bf16x8 b = bfr[(size_t)nt * 64];
        acc[0][nt] = __builtin_amdgcn_mfma_f32_16x16x32_bf16(a0, b, acc[0][nt], 0, 0, 0);
        acc[1][nt] = __builtin_amdgcn_mfma_f32_16x16x32_bf16(a1, b, acc[1][nt], 0, 0, 0);
      }
    }
  }
  if (A2){
    const __hip_bfloat16* a0p = A2 + (size_t)r0 * DD + koff;
    const __hip_bfloat16* a1p = A2 + (size_t)r1 * DD + koff;
    for (int k0 = 0; k0 < K2; k0 += 32, ++ktile){
      bf16x8 a0 = *(const bf16x8*)(a0p + k0);
      bf16x8 a1 = *(const bf16x8*)(a1p + k0);
      const bf16x8* bfr = (const bf16x8*)(Bp + (((size_t)ktile * ntt + nt0) * 64 + lane) * 8);
      #pragma unroll
      for (int nt = 0; nt < 8; nt++){
        bf16x8 b = bfr[(size_t)nt * 64];
        acc[0][nt] = __builtin_amdgcn_mfma_f32_16x16x32_bf16(a0, b, acc[0][nt], 0, 0, 0);
        acc[1][nt] = __builtin_amdgcn_mfma_f32_16x16x32_bf16(a1, b, acc[1][nt], 0, 0, 0);
      }
    }
  }

  const int colb = lane & 15;
  const int lq = lane >> 4;

  float bias8[8], g8[8], b8[8];
  #pragma unroll
  for (int nt = 0; nt < 8; nt++){
    int c = (nt << 4) + colb;
    bias8[nt] = bias ? bias[c] : 0.f;
    if (MODE == 1){ g8[nt] = ln_g[c]; b8[nt] = ln_b[c]; }
  }

  #pragma unroll
  for (int mt = 0; mt < 2; mt++){
    #pragma unroll
    for (int j = 0; j < 4; j++){
      int row = mbase + mt * 16 + lq * 4 + j;
      if (MODE == 1){
        float v[8]; float s = 0.f;
        #pragma unroll
        for (int nt = 0; nt < 8; nt++){ v[nt] = acc[mt][nt][j] + bias8[nt]; s += v[nt]; }
        #pragma unroll
        for (int o = 1; o < 16; o <<= 1) s += __shfl_xor(s, o);
        float mu = s * (1.f / 128.f);
        float q = 0.f;
        #pragma unroll
        for (int nt = 0; nt < 8; nt++){ float dd = v[nt] - mu; q += dd * dd; }
        #pragma unroll
        for (int o = 1; o < 16; o <<= 1) q += __shfl_xor(q, o);
        float rstd = rsqrtf(q * (1.f / 128.f) + 1e-5f);
        if (row < M){
          #pragma unroll
          for (int nt = 0; nt < 8; nt++){
            float y = leaky((v[nt] - mu) * rstd * g8[nt] + b8[nt], 0.1f);
            Cb[(size_t)row * ldc + (nt << 4) + colb] = __float2bfloat16(y);
          }
        }
      } else { // MODE 3: bias + L2 normalize, fp32 out
        float v[8]; float q = 0.f;
        #pragma unroll
        for (int nt = 0; nt < 8; nt++){ v[nt] = acc[mt][nt][j] + bias8[nt]; q += v[nt] * v[nt]; }
        #pragma unroll
        for (int o = 1; o < 16; o <<= 1) q += __shfl_xor(q, o);
        float sc = 1.0f / fmaxf(sqrtf(q), 1e-12f);
        if (row < M){
          #pragma unroll
          for (int nt = 0; nt < 8; nt++)
            Cf[(size_t)row * ldc + (nt << 4) + colb] = v[nt] * sc;
        }
      }
    }
  }
}

// ---------------- GAT: per-dst softmax coefficients (one THREAD per dst) ----------------
__global__ void k_gat_coef(const int* __restrict__ ptr, const int* __restrict__ esrc,
                           const float* __restrict__ aS, const float* __restrict__ aD,
                           float* __restrict__ cf, float* __restrict__ cfS,
                           float* __restrict__ den, int N_){
  int t = blockIdx.x * 256 + threadIdx.x;
  if (t >= N_) return;
  int beg = ptr[t * 8], end = ptr[t * 8 + 8];
  float4 ad = *(const float4*)(aD + (size_t)t * 4);
  float4 as = *(const float4*)(aS + (size_t)t * 4);
  float m0 = leaky(as.x + ad.x, 0.2f), m1 = leaky(as.y + ad.y, 0.2f);
  float m2 = leaky(as.z + ad.z, 0.2f), m3 = leaky(as.w + ad.w, 0.2f);
  for (int e = beg; e < end; e++){
    float4 a = *(const float4*)(aS + (size_t)esrc[e] * 4);
    m0 = fmaxf(m0, leaky(a.x + ad.x, 0.2f));
    m1 = fmaxf(m1, leaky(a.y + ad.y, 0.2f));
    m2 = fmaxf(m2, leaky(a.z + ad.z, 0.2f));
    m3 = fmaxf(m3, leaky(a.w + ad.w, 0.2f));
  }
  float s0 = __expf(leaky(as.x + ad.x, 0.2f) - m0);
  float s1 = __expf(leaky(as.y + ad.y, 0.2f) - m1);
  float s2 = __expf(leaky(as.z + ad.z, 0.2f) - m2);
  float s3 = __expf(leaky(as.w + ad.w, 0.2f) - m3);
  *(float4*)(cfS + (size_t)t * 4) = make_float4(s0, s1, s2, s3);
  float d0 = s0, d1 = s1, d2 = s2, d3 = s3;
  for (int e = beg; e < end; e++){
    float4 a = *(const float4*)(aS + (size_t)esrc[e] * 4);
    float x0 = __expf(leaky(a.x + ad.x, 0.2f) - m0);
    float x1 = __expf(leaky(a.y + ad.y, 0.2f) - m1);
    float x2 = __expf(leaky(a.z + ad.z, 0.2f) - m2);
    float x3 = __expf(leaky(a.w + ad.w, 0.2f) - m3);
    *(float4*)(cf + (size_t)e * 4) = make_float4(x0, x1, x2, x3);
    d0 += x0; d1 += x1; d2 += x2; d3 += x3;
  }
  *(float4*)(den + (size_t)t * 4) = make_float4(d0, d1, d2, d3);
}

extern "C" void kernel_launch(void* const* d_in, const int* in_sizes, int n_in,
                              void* d_out, int out_size, void* d_ws, size_t ws_size,
                              hipStream_t stream){
  const float* x       = (const float*)d_in[0];
  const int*   ei      = (const int*)d_in[1];
  const int*   et      = (const int*)d_in[2];
  const float* r0_basis= (const float*)d_in[3];  const float* r0_comp = (const float*)d_in[4];
  const float* r0_root = (const float*)d_in[5];  const float* r0_bias = (const float*)d_in[6];
  const float* ln0_g   = (const float*)d_in[7];  const float* ln0_b   = (const float*)d_in[8];
  const float* r1_basis= (const float*)d_in[9];  const float* r1_comp = (const float*)d_in[10];
  const float* r1_root = (const float*)d_in[11]; const float* r1_bias = (const float*)d_in[12];
  const float* ln1_g   = (const float*)d_in[13]; const float* ln1_b   = (const float*)d_in[14];
  const float* gat_w   = (const float*)d_in[15]; const float* gat_asrc= (const float*)d_in[16];
  const float* gat_adst= (const float*)d_in[17]; const float* gat_bias= (const float*)d_in[18];
  const float* ln2_g   = (const float*)d_in[19]; const float* ln2_b   = (const float*)d_in[20];
  const float* r2_basis= (const float*)d_in[21]; const float* r2_comp = (const float*)d_in[22];
  const float* r2_root = (const float*)d_in[23]; const float* r2_bias = (const float*)d_in[24];

  const int N_ = in_sizes[0] / DD;
  const int E_ = in_sizes[2];
  const int NK = N_ * NKEY8;
  const int* src = ei;
  const int* dst = ei + E_;
  float* T2 = (float*)d_out;

  char* wp_ = (char*)d_ws;
  auto alloc = [&](size_t b)->void*{ void* p = wp_; wp_ += (b + 255) & ~(size_t)255; return p; };
  __hip_bfloat16* agg16 = (__hip_bfloat16*)alloc((size_t)N_ * LDA_AGG * 2);  // also hosts z16
  __hip_bfloat16* xb16  = (__hip_bfloat16*)alloc((size_t)N_ * DD * 2);
  float*          inv   = (float*)alloc((size_t)NK * 4);
  int*            ptrb  = (int*)alloc((size_t)(NK + 1) * 4);
  int*            cnt   = (int*)alloc((size_t)NK * 4);
  int*            run   = (int*)alloc((size_t)NK * 4);
  int*            esrc  = (int*)alloc((size_t)E_ * 4);
  int*            part  = (int*)alloc(512 * 4);
  float*          aS    = (float*)alloc((size_t)N_ * 4 * 4);
  float*          aD    = (float*)alloc((size_t)N_ * 4 * 4);
  float*          cf    = (float*)alloc((size_t)E_ * 4 * 4);
  float*          cfS   = (float*)alloc((size_t)N_ * 4 * 4);
  float*          den   = (float*)alloc((size_t)N_ * 4 * 4);
  float*          vT    = (float*)alloc((size_t)2 * 512 * 4);
  __hip_bfloat16* Wp    = (__hip_bfloat16*)alloc((size_t)1152 * 128 * 2);
  __hip_bfloat16* WpZ   = (__hip_bfloat16*)alloc((size_t)512 * 128 * 2);
  if ((size_t)(wp_ - (char*)d_ws) > ws_size) return;
  __hip_bfloat16* z16 = agg16;   // aliased: agg dead when z is live, and vice versa

  const int Mb = (N_ + 127) / 128;
  const int nScanB = (NK + 1023) / 1024;

  // ---- CSR build (same graph for all layers) ----
  hipMemsetAsync(cnt, 0, (size_t)NK * 4, stream);
  k_hist<<<(E_ + 255) / 256, 256, 0, stream>>>(dst, et, cnt, E_);
  k_scan1<<<nScanB, 256, 0, stream>>>(cnt, ptrb, part, NK);
  k_scan2<<<1, 512, 0, stream>>>(part, nScanB);
  k_scan3<<<(NK + 1 + 255) / 256, 256, 0, stream>>>(ptrb, part, NK, E_);
  k_inv<<<(NK + 255) / 256, 256, 0, stream>>>(ptrb, inv, NK);
  hipMemcpyAsync(run, ptrb, (size_t)NK * 4, hipMemcpyDeviceToDevice, stream);
  k_scatter_pos<<<(E_ + 255) / 256, 256, 0, stream>>>(src, dst, et, run, esrc, E_);
  k_cvt<<<(N_ * DD + 255) / 256, 256, 0, stream>>>(x, xb16, N_ * DD);

  // ---- RGCN layer 0 (LN0+leaky fused) ----
  k_makeW<<<576, 256, 0, stream>>>(r0_basis, r0_comp, r0_root, Wp);
  k_csr_agg<<<(N_ + 3) / 4, 256, 0, stream>>>(ptrb, esrc, inv, xb16, agg16, N_);
  k_gemm_mfma<1><<<dim3(Mb, 1), 256, 0, stream>>>(agg16, LDA_AGG, 1024, xb16, 128, N_, Wp, 8,
      r0_bias, ln0_g, ln0_b, nullptr, xb16, DD);

  // ---- RGCN layer 1 (LN1+leaky fused) ----
  k_makeW<<<576, 256, 0, stream>>>(r1_basis, r1_comp, r1_root, Wp);
  k_csr_agg<<<(N_ + 3) / 4, 256, 0, stream>>>(ptrb, esrc, inv, xb16, agg16, N_);
  k_gemm_mfma<1><<<dim3(Mb, 1), 256, 0, stream>>>(agg16, LDA_AGG, 1024, xb16, 128, N_, Wp, 8,
      r1_bias, ln1_g, ln1_b, nullptr, xb16, DD);

  // ---- GAT: logits from x (no hH), coef, z-aggregate, K=512 GEMM (+bias+LN2 fused) ----
  k_valpha<<<4, 256, 0, stream>>>(gat_w, gat_asrc, gat_adst, vT);
  k_packGZ<<<256, 256, 0, stream>>>(gat_w, WpZ);
  k_av<<<(N_ + 3) / 4, 256, 0, stream>>>(xb16, vT, aS, aD, N_);
  k_gat_coef<<<(N_ + 255) / 256, 256, 0, stream>>>(ptrb, esrc, aS, aD, cf, cfS, den, N_);
  k_zagg<<<(N_ + 3) / 4, 256, 0, stream>>>(ptrb, esrc, cf, cfS, den, xb16, z16, N_);
  k_gemm_mfma<1><<<dim3(Mb, 1), 256, 0, stream>>>(z16, 512, 512, nullptr, 0, N_, WpZ, 8,
      gat_bias, ln2_g, ln2_b, nullptr, xb16, DD);

  // ---- RGCN layer 2 -> d_out (fp32), L2 normalize fused in epilogue ----
  k_makeW<<<576, 256, 0, stream>>>(r2_basis, r2_comp, r2_root, Wp);
  k_csr_agg<<<(N_ + 3) / 4, 256, 0, stream>>>(ptrb, esrc, inv, xb16, agg16, N_);
  k_gemm_mfma<3><<<dim3(Mb, 1), 256, 0, stream>>>(agg16, LDA_AGG, 1024, xb16, 128, N_, Wp, 8,
      r2_bias, nullptr, nullptr, T2, nullptr, DD);
}